// Round 7
// baseline (522.178 us; speedup 1.0000x reference)
//
#include <hip/hip_runtime.h>

// ---------------- problem constants ----------------
#define NN      50000      // nodes
#define NE      500000     // edges (before self loops)
#define NET     550000     // edges + self loops
#define IND     256        // input dim
#define HC      512        // heads*hidden
#define NH      4          // heads
#define NG      512        // graphs
#define NCLS    10

typedef __attribute__((ext_vector_type(8))) _Float16 f16x8;
typedef __attribute__((ext_vector_type(4))) float f32x4;
typedef __attribute__((ext_vector_type(4))) ushort us4;

// ---------------- scalar convert helpers ----------------
__device__ __forceinline__ ushort f2bf(float x) {      // fp32 -> bf16 (RNE)
    unsigned u = __float_as_uint(x);
    u += 0x7fffu + ((u >> 16) & 1u);
    return (ushort)(u >> 16);
}
__device__ __forceinline__ float bf2f(ushort h) {
    return __uint_as_float((unsigned)h << 16);
}
__device__ __forceinline__ ushort f2h(float x) {       // fp32 -> fp16 bits (RNE)
    union { _Float16 h; ushort u; } cv;
    cv.h = (_Float16)x;
    return cv.u;
}

// async global->LDS, 16B per lane. dst must be wave-uniform base (+lane*16 by HW).
__device__ __forceinline__ void gload_lds16(const void* g, void* s) {
    __builtin_amdgcn_global_load_lds(
        (const __attribute__((address_space(1))) unsigned*)g,
        (__attribute__((address_space(3))) unsigned*)s, 16, 0, 0);
}

// ---------------- fp16 MFMA GEMM + fused attention coefficients ----------
// zbf[M,512] = bf16(A[M,K] @ B[K,512]);  as/ad[row,head] = dot(z_row_head, a_*)
// computed from fp32 acc in-register (block covers 128 rows x one head).
__global__ __launch_bounds__(256) void k_gemm_f16(
    const ushort* __restrict__ A, const ushort* __restrict__ BT,
    const float* __restrict__ a_srcv, const float* __restrict__ a_dstv,
    ushort* __restrict__ Cbf, float* __restrict__ as_b, float* __restrict__ ad_b,
    int M, int K)
{
    __shared__ __align__(16) ushort As[128 * 64];
    __shared__ __align__(16) ushort Bs[128 * 64];
    __shared__ float sred[2][128];

    const int tid = threadIdx.x;
    const int nwg = gridDim.x;
    const int orig = blockIdx.x;
    const int q = nwg >> 3, r = nwg & 7, xcd = orig & 7;
    const int wgid = (xcd < r ? xcd * (q + 1) : r * (q + 1) + (xcd - r) * q) + (orig >> 3);
    const int bm = (wgid >> 2) * 128;
    const int bn = (wgid & 3) * 128;

    const int l = tid & 63;
    const int w = tid >> 6;
    const int wm = (w >> 1) * 64, wn = (w & 1) * 64;
    const int fr = l & 15;
    const int fk = (l >> 4) * 8;

    if (tid < 128) { sred[0][tid] = 0.f; sred[1][tid] = 0.f; }

    f32x4 zero = {0.f, 0.f, 0.f, 0.f};
    f32x4 acc[4][4];
#pragma unroll
    for (int m = 0; m < 4; ++m)
#pragma unroll
        for (int n = 0; n < 4; ++n) acc[m][n] = zero;

    const int nsteps = K >> 6;
    const int wbase = (tid & 0xC0) << 4;       // wave-uniform byte base

    for (int ks = 0; ks < nsteps; ++ks) {
        int k0 = ks << 6;
#pragma unroll
        for (int i = 0; i < 4; ++i) {
            int c = i * 256 + tid;
            int row = c >> 3;
            int col16 = (c & 7) ^ (row & 7);
            int arow = bm + row; arow = arow < M ? arow : M - 1;
            gload_lds16(A + (size_t)arow * K + k0 + (col16 << 3),
                        (char*)As + i * 4096 + wbase);
        }
#pragma unroll
        for (int i = 0; i < 4; ++i) {
            int c = i * 256 + tid;
            int j = c >> 3;
            int col16 = (c & 7) ^ (j & 7);
            gload_lds16(BT + (size_t)(bn + j) * K + k0 + (col16 << 3),
                        (char*)Bs + i * 4096 + wbase);
        }
        __syncthreads();
#pragma unroll
        for (int kk = 0; kk < 64; kk += 32) {
            f16x8 a[4], b[4];
            int kb = (kk + fk) >> 3;
#pragma unroll
            for (int m = 0; m < 4; ++m) {
                int row = wm + m * 16 + fr;
                a[m] = *(const f16x8*)((const char*)As + row * 128 + ((kb ^ (row & 7)) << 4));
            }
#pragma unroll
            for (int n = 0; n < 4; ++n) {
                int col = wn + n * 16 + fr;
                b[n] = *(const f16x8*)((const char*)Bs + col * 128 + ((kb ^ (col & 7)) << 4));
            }
#pragma unroll
            for (int m = 0; m < 4; ++m)
#pragma unroll
                for (int n = 0; n < 4; ++n)
                    acc[m][n] = __builtin_amdgcn_mfma_f32_16x16x32_f16(a[m], b[n], acc[m][n], 0, 0, 0);
        }
        __syncthreads();
    }

    // ---- epilogue: bf16 z mirror + fused as/ad ----
    // C/D layout: col = lane&15, row = (lane>>4)*4 + reg
    const int hh = bn >> 7;                    // this block's head
    float asl[4], adl[4];
#pragma unroll
    for (int n = 0; n < 4; ++n) {
        int c = wn + n * 16 + fr;
        asl[n] = a_srcv[hh * 128 + c];
        adl[n] = a_dstv[hh * 128 + c];
    }
    const int rbase = (l >> 4) * 4;
#pragma unroll
    for (int m = 0; m < 4; ++m) {
#pragma unroll
        for (int rr = 0; rr < 4; ++rr) {
            int rloc = wm + m * 16 + rbase + rr;
            int rowi = bm + rloc;
            float ps = 0.f, pd = 0.f;
#pragma unroll
            for (int n = 0; n < 4; ++n) {
                float v = acc[m][n][rr];
                ps += v * asl[n];
                pd += v * adl[n];
                if (rowi < M) Cbf[(size_t)rowi * HC + bn + wn + n * 16 + fr] = f2bf(v);
            }
#pragma unroll
            for (int off = 1; off < 16; off <<= 1) {
                ps += __shfl_xor(ps, off, 64);
                pd += __shfl_xor(pd, off, 64);
            }
            if (fr == 0) {
                atomicAdd(&sred[0][rloc], ps);
                atomicAdd(&sred[1][rloc], pd);
            }
        }
    }
    __syncthreads();
    if (tid < 128) {
        int rowi = bm + tid;
        if (rowi < M) {
            as_b[rowi * 4 + hh] = sred[0][tid];
            ad_b[rowi * 4 + hh] = sred[1][tid];
        }
    }
}

// ---------------- conversions ----------------
__global__ void k_cvt_f16(const float* __restrict__ in, ushort* __restrict__ o,
                          int n4) {
    int i = blockIdx.x * blockDim.x + threadIdx.x;
    if (i >= n4) return;
    float4 v = ((const float4*)in)[i];
    ushort4 h;
    h.x = f2h(v.x); h.y = f2h(v.y); h.z = f2h(v.z); h.w = f2h(v.w);
    ((ushort4*)o)[i] = h;
}

// W[K][512] -> WT[512][K] fp16
__global__ void k_cvt_wT(const float* __restrict__ W, ushort* __restrict__ hT,
                         int K, int logK) {
    int id = blockIdx.x * blockDim.x + threadIdx.x;
    if (id >= (HC << logK)) return;
    int nn = id >> logK, k = id & (K - 1);
    hT[id] = f2h(W[(size_t)k * HC + nn]);
}

// ---------------- CSR build ----------------
__global__ void k_deg(const int* __restrict__ ei, int* __restrict__ deg) {
    int e = blockIdx.x * blockDim.x + threadIdx.x;
    if (e >= NET) return;
    int d = (e < NE) ? ei[NE + e] : (e - NE);
    atomicAdd(&deg[d], 1);
}

__global__ __launch_bounds__(1024) void k_scan(const int* __restrict__ cnt,
                                               int* __restrict__ off, int n) {
    __shared__ int sums[1024];
    const int tid = threadIdx.x;
    const int chunk = (n + 1023) >> 10;
    const int beg = tid * chunk;
    const int end = min(beg + chunk, n);
    int s = 0;
    for (int i = beg; i < end; ++i) s += cnt[i];
    sums[tid] = s;
    __syncthreads();
    for (int d = 1; d < 1024; d <<= 1) {
        int t = (tid >= d) ? sums[tid - d] : 0;
        __syncthreads();
        sums[tid] += t;
        __syncthreads();
    }
    int run = (tid == 0) ? 0 : sums[tid - 1];
    for (int i = beg; i < end; ++i) { off[i] = run; run += cnt[i]; }
    if (tid == 1023) off[n] = sums[1023];
}

__global__ void k_fill(const int* __restrict__ ei,
                       const int* __restrict__ rowptr,
                       int* __restrict__ fillcnt,
                       int* __restrict__ colsrc) {
    int e = blockIdx.x * blockDim.x + threadIdx.x;
    if (e >= NET) return;
    int s, d;
    if (e < NE) { s = ei[e]; d = ei[NE + e]; } else { s = d = e - NE; }
    int pos = rowptr[d] + atomicAdd(&fillcnt[d], 1);
    colsrc[pos] = s;
}

// ---------------- fused softmax + all-heads weighted gather --------------
// one 128-thread block per node; 4 subgroups of 32 lanes (one per head).
// pass1/2: subgroup-parallel max + expsum (width-32 shfl reduce);
// pass3: weighted z gather, alpha recomputed per edge (as table is L2-hot).
// outputs via non-temporal stores so zbf stays LLC-resident.
// obf16=0: fp16 out (feeds GEMM2); obf16=1: bf16 out (feeds pool).
__global__ __launch_bounds__(128) void k_gather(
    const ushort* __restrict__ zb, const float* __restrict__ as,
    const float* __restrict__ ad, const int* __restrict__ rowptr,
    const int* __restrict__ colsrc, const float* __restrict__ bias,
    ushort* __restrict__ o16, int obf16)
{
    const int node = blockIdx.x;
    const int tid = threadIdx.x;
    const int head = tid >> 5, lane = tid & 31;
    const int beg = rowptr[node], end = rowptr[node + 1];
    const float adn = ad[node * 4 + head];

    // pass 1: max over incoming edges (self-loop guarantees >=1)
    float lm = -3.0e38f;
    for (int e = beg + lane; e < end; e += 32) {
        float ev = as[colsrc[e] * 4 + head] + adn;
        ev = ev > 0.f ? ev : 0.2f * ev;
        lm = fmaxf(lm, ev);
    }
#pragma unroll
    for (int off = 1; off < 32; off <<= 1) lm = fmaxf(lm, __shfl_xor(lm, off, 32));

    // pass 2: exp-sum
    float ls = 0.f;
    for (int e = beg + lane; e < end; e += 32) {
        float ev = as[colsrc[e] * 4 + head] + adn;
        ev = ev > 0.f ? ev : 0.2f * ev;
        ls += __expf(ev - lm);
    }
#pragma unroll
    for (int off = 1; off < 32; off <<= 1) ls += __shfl_xor(ls, off, 32);
    const float dinv = 1.0f / (ls + 1e-16f);

    // pass 3: weighted feature gather (unnormalized weights, scale at end)
    const ushort* __restrict__ zh = zb + head * 128 + (lane << 2);
    float ax = 0.f, ay = 0.f, az = 0.f, aw = 0.f;
    int e = beg;
    for (; e + 2 <= end; e += 2) {
        int s0 = colsrc[e], s1 = colsrc[e + 1];
        float e0 = as[s0 * 4 + head] + adn; e0 = e0 > 0.f ? e0 : 0.2f * e0;
        float e1 = as[s1 * 4 + head] + adn; e1 = e1 > 0.f ? e1 : 0.2f * e1;
        float a0 = __expf(e0 - lm), a1 = __expf(e1 - lm);
        ushort4 u0 = *(const ushort4*)&zh[(size_t)s0 * HC];
        ushort4 u1 = *(const ushort4*)&zh[(size_t)s1 * HC];
        ax += a0 * bf2f(u0.x) + a1 * bf2f(u1.x);
        ay += a0 * bf2f(u0.y) + a1 * bf2f(u1.y);
        az += a0 * bf2f(u0.z) + a1 * bf2f(u1.z);
        aw += a0 * bf2f(u0.w) + a1 * bf2f(u1.w);
    }
    if (e < end) {
        int s0 = colsrc[e];
        float e0 = as[s0 * 4 + head] + adn; e0 = e0 > 0.f ? e0 : 0.2f * e0;
        float a0 = __expf(e0 - lm);
        ushort4 u0 = *(const ushort4*)&zh[(size_t)s0 * HC];
        ax += a0 * bf2f(u0.x); ay += a0 * bf2f(u0.y);
        az += a0 * bf2f(u0.z); aw += a0 * bf2f(u0.w);
    }
    const int col = head * 128 + (lane << 2);
    float4 bv = *(const float4*)&bias[col];
    float rx = fmaxf(ax * dinv + bv.x, 0.f), ry = fmaxf(ay * dinv + bv.y, 0.f);
    float rz = fmaxf(az * dinv + bv.z, 0.f), rw = fmaxf(aw * dinv + bv.w, 0.f);
    us4 h;
    if (obf16) {
        h.x = f2bf(rx); h.y = f2bf(ry); h.z = f2bf(rz); h.w = f2bf(rw);
    } else {
        h.x = f2h(rx); h.y = f2h(ry); h.z = f2h(rz); h.w = f2h(rw);
    }
    __builtin_nontemporal_store(h, (us4*)&o16[(size_t)node * HC + col]);
}

// ---------------- pooling (bf16 input) / classifier ----------------
__global__ void k_gcnt(const int* __restrict__ batch, int* __restrict__ gcnt) {
    int n = blockIdx.x * blockDim.x + threadIdx.x;
    if (n < NN) atomicAdd(&gcnt[batch[n]], 1);
}

__global__ __launch_bounds__(128) void k_pool(const ushort* __restrict__ h,
                                              const int* __restrict__ goff,
                                              const int* __restrict__ gcnt,
                                              float* __restrict__ hg) {
    const int g = blockIdx.x;
    const int tid = threadIdx.x;
    const int beg = goff[g];
    const int cnt = gcnt[g];
    float4 acc = make_float4(0.f, 0.f, 0.f, 0.f);
    for (int r = beg; r < beg + cnt; ++r) {
        ushort4 v = *(const ushort4*)&h[(size_t)r * HC + (tid << 2)];
        acc.x += bf2f(v.x); acc.y += bf2f(v.y);
        acc.z += bf2f(v.z); acc.w += bf2f(v.w);
    }
    float inv = 1.0f / (float)max(cnt, 1);
    *(float4*)&hg[(size_t)g * HC + (tid << 2)] =
        make_float4(acc.x * inv, acc.y * inv, acc.z * inv, acc.w * inv);
}

__global__ __launch_bounds__(64) void k_cls(const float* __restrict__ hg,
                                            const float* __restrict__ Wc,
                                            const float* __restrict__ bc,
                                            float* __restrict__ out) {
    const int g = blockIdx.x;
    const int lane = threadIdx.x;
#pragma unroll 1
    for (int cls = 0; cls < NCLS; ++cls) {
        float p = 0.f;
#pragma unroll
        for (int j = 0; j < 8; ++j) {
            int c = lane + j * 64;
            p += hg[(size_t)g * HC + c] * Wc[c * NCLS + cls];
        }
#pragma unroll
        for (int off = 32; off; off >>= 1) p += __shfl_down(p, off, 64);
        if (lane == 0) out[g * NCLS + cls] = p + bc[cls];
    }
}

// ---------------- launch ----------------
extern "C" void kernel_launch(void* const* d_in, const int* in_sizes, int n_in,
                              void* d_out, int out_size, void* d_ws, size_t ws_size,
                              hipStream_t stream) {
    const float* x     = (const float*)d_in[0];
    const int*   ei    = (const int*)d_in[1];
    const int*   batch = (const int*)d_in[2];
    const float* W1    = (const float*)d_in[3];
    const float* asrc1 = (const float*)d_in[4];
    const float* adst1 = (const float*)d_in[5];
    const float* b1    = (const float*)d_in[6];
    const float* W2    = (const float*)d_in[7];
    const float* asrc2 = (const float*)d_in[8];
    const float* adst2 = (const float*)d_in[9];
    const float* b2    = (const float*)d_in[10];
    const float* Wc    = (const float*)d_in[11];
    const float* bc    = (const float*)d_in[12];
    float* out = (float*)d_out;
    (void)in_sizes; (void)n_in; (void)out_size; (void)ws_size;

    // ---- big region (102.4 MB), lifetimes sequential on stream:
    // MB offsets:   0 (region A, 51.2)     51.2 (region B, 51.2)
    // cvt/GEMM1:    [zbf 51.2 (write)  ]   [xf16 25.6 (read by GEMM1)]
    // gather1:      [zbf (read)        ]   [h1f16 51.2 (nt write)    ]
    // GEMM2:        [zbf 51.2 (write)  ]   [h1f16 (read)             ]
    // gather2:      [zbf (read)        ]   [h2b bf16 51.2 (nt write) ]
    // pool:         [  --              ]   [h2b (read)               ]
    char* R = (char*)d_ws;
    const size_t MB512 = (size_t)NN * HC;        // 25.6M elements
    ushort* zbf   = (ushort*)R;
    ushort* xf16  = (ushort*)(R + MB512 * 2);
    ushort* h1f16 = (ushort*)(R + MB512 * 2);
    ushort* h2b   = (ushort*)(R + MB512 * 2);

    char* w = R + MB512 * 4;
    size_t off = 0;
    auto alloc = [&](size_t bytes) {
        void* p = w + off;
        off += (bytes + 255) & ~(size_t)255;
        return p;
    };
    float* as_b = (float*)alloc((size_t)NN * NH * 4);
    float* ad_b = (float*)alloc((size_t)NN * NH * 4);
    int* rowptr = (int*)alloc((size_t)(NN + 1) * 4);
    int* deg    = (int*)alloc((size_t)NN * 4);
    int* colsrc = (int*)alloc((size_t)NET * 4);
    int* gcnt   = (int*)alloc((size_t)NG * 4);
    int* goff   = (int*)alloc((size_t)(NG + 1) * 4);
    float* hg   = (float*)alloc((size_t)NG * HC * 4);
    ushort* W1T = (ushort*)alloc((size_t)HC * IND * 2);
    ushort* W2T = (ushort*)alloc((size_t)HC * HC * 2);

    const int EB = 256, EG = (NET + EB - 1) / EB;
    const int MT = (NN + 127) / 128;

    // ---- conversions ----
    k_cvt_f16<<<(NN * IND / 4 + 255) / 256, 256, 0, stream>>>(x, xf16, NN * IND / 4);
    k_cvt_wT<<<(HC * IND + 255) / 256, 256, 0, stream>>>(W1, W1T, IND, 8);
    k_cvt_wT<<<(HC * HC + 255) / 256, 256, 0, stream>>>(W2, W2T, HC, 9);

    // ---- CSR build ----
    hipMemsetAsync(deg, 0, (size_t)NN * 4, stream);
    k_deg<<<EG, EB, 0, stream>>>(ei, deg);
    k_scan<<<1, 1024, 0, stream>>>(deg, rowptr, NN);
    hipMemsetAsync(deg, 0, (size_t)NN * 4, stream);
    k_fill<<<EG, EB, 0, stream>>>(ei, rowptr, deg, colsrc);

    // ---- graph offsets ----
    hipMemsetAsync(gcnt, 0, (size_t)NG * 4, stream);
    k_gcnt<<<(NN + 255) / 256, 256, 0, stream>>>(batch, gcnt);
    k_scan<<<1, 1024, 0, stream>>>(gcnt, goff, NG);

    // ================= layer 1 =================
    k_gemm_f16<<<MT * 4, 256, 0, stream>>>(xf16, W1T, asrc1, adst1,
                                           zbf, as_b, ad_b, NN, IND);
    k_gather<<<NN, 128, 0, stream>>>(zbf, as_b, ad_b, rowptr, colsrc, b1,
                                     h1f16, 0);

    // ================= layer 2 =================
    k_gemm_f16<<<MT * 4, 256, 0, stream>>>(h1f16, W2T, asrc2, adst2,
                                           zbf, as_b, ad_b, NN, HC);
    k_gather<<<NN, 128, 0, stream>>>(zbf, as_b, ad_b, rowptr, colsrc, b2,
                                     h2b, 1);

    // ================= pool + classify =================
    k_pool<<<NG, 128, 0, stream>>>(h2b, goff, gcnt, hg);
    k_cls<<<NG, 64, 0, stream>>>(hg, Wc, bc, out);
}

// Round 8
// 513.212 us; speedup vs baseline: 1.0175x; 1.0175x over previous
//
#include <hip/hip_runtime.h>

// ---------------- problem constants ----------------
#define NN      50000      // nodes
#define NE      500000     // edges (before self loops)
#define NET     550000     // edges + self loops
#define IND     256        // input dim
#define HC      512        // heads*hidden
#define NH      4          // heads
#define NG      512        // graphs
#define NCLS    10

typedef __attribute__((ext_vector_type(8))) _Float16 f16x8;
typedef __attribute__((ext_vector_type(4))) float f32x4;
typedef __attribute__((ext_vector_type(4))) ushort us4;

// ---------------- scalar convert helpers ----------------
__device__ __forceinline__ ushort f2bf(float x) {      // fp32 -> bf16 (RNE)
    unsigned u = __float_as_uint(x);
    u += 0x7fffu + ((u >> 16) & 1u);
    return (ushort)(u >> 16);
}
__device__ __forceinline__ float bf2f(ushort h) {
    return __uint_as_float((unsigned)h << 16);
}
__device__ __forceinline__ ushort f2h(float x) {       // fp32 -> fp16 bits (RNE)
    union { _Float16 h; ushort u; } cv;
    cv.h = (_Float16)x;
    return cv.u;
}

// async global->LDS, 16B per lane. dst must be wave-uniform base (+lane*16 by HW).
__device__ __forceinline__ void gload_lds16(const void* g, void* s) {
    __builtin_amdgcn_global_load_lds(
        (const __attribute__((address_space(1))) unsigned*)g,
        (__attribute__((address_space(3))) unsigned*)s, 16, 0, 0);
}

// ---------------- fp16 MFMA GEMM + fused attention coefficients ----------
// zbf[M,512] = bf16(A[M,K] @ B[K,512]);  as/ad[row,head] = dot(z_row_head, a_*)
// computed from fp32 acc in-register (block covers 128 rows x one head).
__global__ __launch_bounds__(256) void k_gemm_f16(
    const ushort* __restrict__ A, const ushort* __restrict__ BT,
    const float* __restrict__ a_srcv, const float* __restrict__ a_dstv,
    ushort* __restrict__ Cbf, float* __restrict__ as_b, float* __restrict__ ad_b,
    int M, int K)
{
    __shared__ __align__(16) ushort As[128 * 64];
    __shared__ __align__(16) ushort Bs[128 * 64];
    __shared__ float sred[2][128];

    const int tid = threadIdx.x;
    const int nwg = gridDim.x;
    const int orig = blockIdx.x;
    const int q = nwg >> 3, r = nwg & 7, xcd = orig & 7;
    const int wgid = (xcd < r ? xcd * (q + 1) : r * (q + 1) + (xcd - r) * q) + (orig >> 3);
    const int bm = (wgid >> 2) * 128;
    const int bn = (wgid & 3) * 128;

    const int l = tid & 63;
    const int w = tid >> 6;
    const int wm = (w >> 1) * 64, wn = (w & 1) * 64;
    const int fr = l & 15;
    const int fk = (l >> 4) * 8;

    if (tid < 128) { sred[0][tid] = 0.f; sred[1][tid] = 0.f; }

    f32x4 zero = {0.f, 0.f, 0.f, 0.f};
    f32x4 acc[4][4];
#pragma unroll
    for (int m = 0; m < 4; ++m)
#pragma unroll
        for (int n = 0; n < 4; ++n) acc[m][n] = zero;

    const int nsteps = K >> 6;
    const int wbase = (tid & 0xC0) << 4;       // wave-uniform byte base

    for (int ks = 0; ks < nsteps; ++ks) {
        int k0 = ks << 6;
#pragma unroll
        for (int i = 0; i < 4; ++i) {
            int c = i * 256 + tid;
            int row = c >> 3;
            int col16 = (c & 7) ^ (row & 7);
            int arow = bm + row; arow = arow < M ? arow : M - 1;
            gload_lds16(A + (size_t)arow * K + k0 + (col16 << 3),
                        (char*)As + i * 4096 + wbase);
        }
#pragma unroll
        for (int i = 0; i < 4; ++i) {
            int c = i * 256 + tid;
            int j = c >> 3;
            int col16 = (c & 7) ^ (j & 7);
            gload_lds16(BT + (size_t)(bn + j) * K + k0 + (col16 << 3),
                        (char*)Bs + i * 4096 + wbase);
        }
        __syncthreads();
#pragma unroll
        for (int kk = 0; kk < 64; kk += 32) {
            f16x8 a[4], b[4];
            int kb = (kk + fk) >> 3;
#pragma unroll
            for (int m = 0; m < 4; ++m) {
                int row = wm + m * 16 + fr;
                a[m] = *(const f16x8*)((const char*)As + row * 128 + ((kb ^ (row & 7)) << 4));
            }
#pragma unroll
            for (int n = 0; n < 4; ++n) {
                int col = wn + n * 16 + fr;
                b[n] = *(const f16x8*)((const char*)Bs + col * 128 + ((kb ^ (col & 7)) << 4));
            }
#pragma unroll
            for (int m = 0; m < 4; ++m)
#pragma unroll
                for (int n = 0; n < 4; ++n)
                    acc[m][n] = __builtin_amdgcn_mfma_f32_16x16x32_f16(a[m], b[n], acc[m][n], 0, 0, 0);
        }
        __syncthreads();
    }

    // ---- epilogue: bf16 z mirror + fused as/ad ----
    // C/D layout: col = lane&15, row = (lane>>4)*4 + reg
    const int hh = bn >> 7;                    // this block's head
    float asl[4], adl[4];
#pragma unroll
    for (int n = 0; n < 4; ++n) {
        int c = wn + n * 16 + fr;
        asl[n] = a_srcv[hh * 128 + c];
        adl[n] = a_dstv[hh * 128 + c];
    }
    const int rbase = (l >> 4) * 4;
#pragma unroll
    for (int m = 0; m < 4; ++m) {
#pragma unroll
        for (int rr = 0; rr < 4; ++rr) {
            int rloc = wm + m * 16 + rbase + rr;
            int rowi = bm + rloc;
            float ps = 0.f, pd = 0.f;
#pragma unroll
            for (int n = 0; n < 4; ++n) {
                float v = acc[m][n][rr];
                ps += v * asl[n];
                pd += v * adl[n];
                if (rowi < M) Cbf[(size_t)rowi * HC + bn + wn + n * 16 + fr] = f2bf(v);
            }
#pragma unroll
            for (int off = 1; off < 16; off <<= 1) {
                ps += __shfl_xor(ps, off, 64);
                pd += __shfl_xor(pd, off, 64);
            }
            if (fr == 0) {
                atomicAdd(&sred[0][rloc], ps);
                atomicAdd(&sred[1][rloc], pd);
            }
        }
    }
    __syncthreads();
    if (tid < 128) {
        int rowi = bm + tid;
        if (rowi < M) {
            as_b[rowi * 4 + hh] = sred[0][tid];
            ad_b[rowi * 4 + hh] = sred[1][tid];
        }
    }
}

// ---------------- conversions ----------------
__global__ void k_cvt_f16(const float* __restrict__ in, ushort* __restrict__ o,
                          int n4) {
    int i = blockIdx.x * blockDim.x + threadIdx.x;
    if (i >= n4) return;
    float4 v = ((const float4*)in)[i];
    ushort4 h;
    h.x = f2h(v.x); h.y = f2h(v.y); h.z = f2h(v.z); h.w = f2h(v.w);
    ((ushort4*)o)[i] = h;
}

// W[K][512] -> WT[512][K] fp16
__global__ void k_cvt_wT(const float* __restrict__ W, ushort* __restrict__ hT,
                         int K, int logK) {
    int id = blockIdx.x * blockDim.x + threadIdx.x;
    if (id >= (HC << logK)) return;
    int nn = id >> logK, k = id & (K - 1);
    hT[id] = f2h(W[(size_t)k * HC + nn]);
}

// ---------------- CSR build ----------------
__global__ void k_deg(const int* __restrict__ ei, int* __restrict__ deg) {
    int e = blockIdx.x * blockDim.x + threadIdx.x;
    if (e >= NET) return;
    int d = (e < NE) ? ei[NE + e] : (e - NE);
    atomicAdd(&deg[d], 1);
}

__global__ __launch_bounds__(1024) void k_scan(const int* __restrict__ cnt,
                                               int* __restrict__ off, int n) {
    __shared__ int sums[1024];
    const int tid = threadIdx.x;
    const int chunk = (n + 1023) >> 10;
    const int beg = tid * chunk;
    const int end = min(beg + chunk, n);
    int s = 0;
    for (int i = beg; i < end; ++i) s += cnt[i];
    sums[tid] = s;
    __syncthreads();
    for (int d = 1; d < 1024; d <<= 1) {
        int t = (tid >= d) ? sums[tid - d] : 0;
        __syncthreads();
        sums[tid] += t;
        __syncthreads();
    }
    int run = (tid == 0) ? 0 : sums[tid - 1];
    for (int i = beg; i < end; ++i) { off[i] = run; run += cnt[i]; }
    if (tid == 1023) off[n] = sums[1023];
}

__global__ void k_fill(const int* __restrict__ ei,
                       const int* __restrict__ rowptr,
                       int* __restrict__ fillcnt,
                       int* __restrict__ colsrc) {
    int e = blockIdx.x * blockDim.x + threadIdx.x;
    if (e >= NET) return;
    int s, d;
    if (e < NE) { s = ei[e]; d = ei[NE + e]; } else { s = d = e - NE; }
    int pos = rowptr[d] + atomicAdd(&fillcnt[d], 1);
    colsrc[pos] = s;
}

// ---------------- single-pass softmax-gather ----------------
// Softmax computed WITHOUT max subtraction: |e| <= ~2 by construction
// (as/ad are 128-dots with 0.1-scaled glorot vectors), exp(e) fp32-safe,
// and softmax is shift-invariant -> identical output.
// Block = 256 thr = 8 subgroups of 32 = 4 nodes x 2 heads; each wave holds
// the SAME node's two heads (identical trip counts, zero divergence).
// Grid in 2 head-pair phases -> z working set per phase = 25.6 MB.
// obf16=0: fp16 out (feeds GEMM2); obf16=1: bf16 out (feeds pool).
__global__ __launch_bounds__(256) void k_gather(
    const ushort* __restrict__ zb, const float* __restrict__ as,
    const float* __restrict__ ad, const int* __restrict__ rowptr,
    const int* __restrict__ colsrc, const float* __restrict__ bias,
    ushort* __restrict__ o16, int obf16)
{
    const int npb = NN >> 2;                   // 12500 blocks per phase
    const int hp = blockIdx.x / npb;           // head-pair phase (0,1)
    const int sub = threadIdx.x >> 5;
    const int node = (blockIdx.x % npb) * 4 + (sub >> 1);
    const int head = hp * 2 + (sub & 1);
    const int lane = threadIdx.x & 31;
    const int beg = rowptr[node], end = rowptr[node + 1];
    const float adn = ad[node * 4 + head];
    const ushort* __restrict__ zh = zb + head * 128 + (lane << 2);

    float ls = 0.f;
    float ax = 0.f, ay = 0.f, az = 0.f, aw = 0.f;
    int e = beg;
    for (; e + 4 <= end; e += 4) {
        int s0 = colsrc[e], s1 = colsrc[e + 1], s2 = colsrc[e + 2], s3 = colsrc[e + 3];
        float e0 = as[s0 * 4 + head] + adn; e0 = e0 > 0.f ? e0 : 0.2f * e0;
        float e1 = as[s1 * 4 + head] + adn; e1 = e1 > 0.f ? e1 : 0.2f * e1;
        float e2 = as[s2 * 4 + head] + adn; e2 = e2 > 0.f ? e2 : 0.2f * e2;
        float e3 = as[s3 * 4 + head] + adn; e3 = e3 > 0.f ? e3 : 0.2f * e3;
        float a0 = __expf(e0), a1 = __expf(e1), a2 = __expf(e2), a3 = __expf(e3);
        ushort4 u0 = *(const ushort4*)&zh[(size_t)s0 * HC];
        ushort4 u1 = *(const ushort4*)&zh[(size_t)s1 * HC];
        ushort4 u2 = *(const ushort4*)&zh[(size_t)s2 * HC];
        ushort4 u3 = *(const ushort4*)&zh[(size_t)s3 * HC];
        ls += (a0 + a1) + (a2 + a3);
        ax += a0 * bf2f(u0.x) + a1 * bf2f(u1.x) + a2 * bf2f(u2.x) + a3 * bf2f(u3.x);
        ay += a0 * bf2f(u0.y) + a1 * bf2f(u1.y) + a2 * bf2f(u2.y) + a3 * bf2f(u3.y);
        az += a0 * bf2f(u0.z) + a1 * bf2f(u1.z) + a2 * bf2f(u2.z) + a3 * bf2f(u3.z);
        aw += a0 * bf2f(u0.w) + a1 * bf2f(u1.w) + a2 * bf2f(u2.w) + a3 * bf2f(u3.w);
    }
    for (; e < end; ++e) {
        int s0 = colsrc[e];
        float e0 = as[s0 * 4 + head] + adn; e0 = e0 > 0.f ? e0 : 0.2f * e0;
        float a0 = __expf(e0);
        ushort4 u0 = *(const ushort4*)&zh[(size_t)s0 * HC];
        ls += a0;
        ax += a0 * bf2f(u0.x); ay += a0 * bf2f(u0.y);
        az += a0 * bf2f(u0.z); aw += a0 * bf2f(u0.w);
    }
    const float dinv = 1.0f / (ls + 1e-16f);
    const int col = head * 128 + (lane << 2);
    float4 bv = *(const float4*)&bias[col];
    float rx = fmaxf(ax * dinv + bv.x, 0.f), ry = fmaxf(ay * dinv + bv.y, 0.f);
    float rz = fmaxf(az * dinv + bv.z, 0.f), rw = fmaxf(aw * dinv + bv.w, 0.f);
    us4 h;
    if (obf16) {
        h.x = f2bf(rx); h.y = f2bf(ry); h.z = f2bf(rz); h.w = f2bf(rw);
    } else {
        h.x = f2h(rx); h.y = f2h(ry); h.z = f2h(rz); h.w = f2h(rw);
    }
    __builtin_nontemporal_store(h, (us4*)&o16[(size_t)node * HC + col]);
}

// ---------------- pooling (bf16 input) / classifier ----------------
__global__ void k_gcnt(const int* __restrict__ batch, int* __restrict__ gcnt) {
    int n = blockIdx.x * blockDim.x + threadIdx.x;
    if (n < NN) atomicAdd(&gcnt[batch[n]], 1);
}

__global__ __launch_bounds__(128) void k_pool(const ushort* __restrict__ h,
                                              const int* __restrict__ goff,
                                              const int* __restrict__ gcnt,
                                              float* __restrict__ hg) {
    const int g = blockIdx.x;
    const int tid = threadIdx.x;
    const int beg = goff[g];
    const int cnt = gcnt[g];
    float4 acc = make_float4(0.f, 0.f, 0.f, 0.f);
    for (int r = beg; r < beg + cnt; ++r) {
        ushort4 v = *(const ushort4*)&h[(size_t)r * HC + (tid << 2)];
        acc.x += bf2f(v.x); acc.y += bf2f(v.y);
        acc.z += bf2f(v.z); acc.w += bf2f(v.w);
    }
    float inv = 1.0f / (float)max(cnt, 1);
    *(float4*)&hg[(size_t)g * HC + (tid << 2)] =
        make_float4(acc.x * inv, acc.y * inv, acc.z * inv, acc.w * inv);
}

__global__ __launch_bounds__(64) void k_cls(const float* __restrict__ hg,
                                            const float* __restrict__ Wc,
                                            const float* __restrict__ bc,
                                            float* __restrict__ out) {
    const int g = blockIdx.x;
    const int lane = threadIdx.x;
#pragma unroll 1
    for (int cls = 0; cls < NCLS; ++cls) {
        float p = 0.f;
#pragma unroll
        for (int j = 0; j < 8; ++j) {
            int c = lane + j * 64;
            p += hg[(size_t)g * HC + c] * Wc[c * NCLS + cls];
        }
#pragma unroll
        for (int off = 32; off; off >>= 1) p += __shfl_down(p, off, 64);
        if (lane == 0) out[g * NCLS + cls] = p + bc[cls];
    }
}

// ---------------- launch ----------------
extern "C" void kernel_launch(void* const* d_in, const int* in_sizes, int n_in,
                              void* d_out, int out_size, void* d_ws, size_t ws_size,
                              hipStream_t stream) {
    const float* x     = (const float*)d_in[0];
    const int*   ei    = (const int*)d_in[1];
    const int*   batch = (const int*)d_in[2];
    const float* W1    = (const float*)d_in[3];
    const float* asrc1 = (const float*)d_in[4];
    const float* adst1 = (const float*)d_in[5];
    const float* b1    = (const float*)d_in[6];
    const float* W2    = (const float*)d_in[7];
    const float* asrc2 = (const float*)d_in[8];
    const float* adst2 = (const float*)d_in[9];
    const float* b2    = (const float*)d_in[10];
    const float* Wc    = (const float*)d_in[11];
    const float* bc    = (const float*)d_in[12];
    float* out = (float*)d_out;
    (void)in_sizes; (void)n_in; (void)out_size; (void)ws_size;

    // ---- big region (102.4 MB), lifetimes sequential on stream:
    // MB offsets:   0 (region A, 51.2)     51.2 (region B, 51.2)
    // cvt/GEMM1:    [zbf 51.2 (write)  ]   [xf16 25.6 (read by GEMM1)]
    // gather1:      [zbf (read)        ]   [h1f16 51.2 (nt write)    ]
    // GEMM2:        [zbf 51.2 (write)  ]   [h1f16 (read)             ]
    // gather2:      [zbf (read)        ]   [h2b bf16 51.2 (nt write) ]
    // pool:         [  --              ]   [h2b (read)               ]
    char* R = (char*)d_ws;
    const size_t MB512 = (size_t)NN * HC;        // 25.6M elements
    ushort* zbf   = (ushort*)R;
    ushort* xf16  = (ushort*)(R + MB512 * 2);
    ushort* h1f16 = (ushort*)(R + MB512 * 2);
    ushort* h2b   = (ushort*)(R + MB512 * 2);

    char* w = R + MB512 * 4;
    size_t off = 0;
    auto alloc = [&](size_t bytes) {
        void* p = w + off;
        off += (bytes + 255) & ~(size_t)255;
        return p;
    };
    float* as_b = (float*)alloc((size_t)NN * NH * 4);
    float* ad_b = (float*)alloc((size_t)NN * NH * 4);
    int* rowptr = (int*)alloc((size_t)(NN + 1) * 4);
    int* deg    = (int*)alloc((size_t)NN * 4);
    int* colsrc = (int*)alloc((size_t)NET * 4);
    int* gcnt   = (int*)alloc((size_t)NG * 4);
    int* goff   = (int*)alloc((size_t)(NG + 1) * 4);
    float* hg   = (float*)alloc((size_t)NG * HC * 4);
    ushort* W1T = (ushort*)alloc((size_t)HC * IND * 2);
    ushort* W2T = (ushort*)alloc((size_t)HC * HC * 2);

    const int EB = 256, EG = (NET + EB - 1) / EB;
    const int MT = (NN + 127) / 128;
    const int GG = 2 * (NN >> 2);                // 2 head-pair phases

    // ---- conversions ----
    k_cvt_f16<<<(NN * IND / 4 + 255) / 256, 256, 0, stream>>>(x, xf16, NN * IND / 4);
    k_cvt_wT<<<(HC * IND + 255) / 256, 256, 0, stream>>>(W1, W1T, IND, 8);
    k_cvt_wT<<<(HC * HC + 255) / 256, 256, 0, stream>>>(W2, W2T, HC, 9);

    // ---- CSR build ----
    hipMemsetAsync(deg, 0, (size_t)NN * 4, stream);
    k_deg<<<EG, EB, 0, stream>>>(ei, deg);
    k_scan<<<1, 1024, 0, stream>>>(deg, rowptr, NN);
    hipMemsetAsync(deg, 0, (size_t)NN * 4, stream);
    k_fill<<<EG, EB, 0, stream>>>(ei, rowptr, deg, colsrc);

    // ---- graph offsets ----
    hipMemsetAsync(gcnt, 0, (size_t)NG * 4, stream);
    k_gcnt<<<(NN + 255) / 256, 256, 0, stream>>>(batch, gcnt);
    k_scan<<<1, 1024, 0, stream>>>(gcnt, goff, NG);

    // ================= layer 1 =================
    k_gemm_f16<<<MT * 4, 256, 0, stream>>>(xf16, W1T, asrc1, adst1,
                                           zbf, as_b, ad_b, NN, IND);
    k_gather<<<GG, 256, 0, stream>>>(zbf, as_b, ad_b, rowptr, colsrc, b1,
                                     h1f16, 0);

    // ================= layer 2 =================
    k_gemm_f16<<<MT * 4, 256, 0, stream>>>(h1f16, W2T, asrc2, adst2,
                                           zbf, as_b, ad_b, NN, HC);
    k_gather<<<GG, 256, 0, stream>>>(zbf, as_b, ad_b, rowptr, colsrc, b2,
                                     h2b, 1);

    // ================= pool + classify =================
    k_pool<<<NG, 128, 0, stream>>>(h2b, goff, gcnt, hg);
    k_cls<<<NG, 64, 0, stream>>>(hg, Wc, bc, out);
}

// Round 9
// 479.640 us; speedup vs baseline: 1.0887x; 1.0700x over previous
//
#include <hip/hip_runtime.h>

// ---------------- problem constants ----------------
#define NN      50000      // nodes
#define NE      500000     // edges (before self loops)
#define NET     550000     // edges + self loops
#define IND     256        // input dim
#define HC      512        // heads*hidden
#define NH      4          // heads
#define NG      512        // graphs
#define NCLS    10

typedef __attribute__((ext_vector_type(8))) _Float16 f16x8;
typedef __attribute__((ext_vector_type(4))) float f32x4;
typedef __attribute__((ext_vector_type(2))) float f32x2;
typedef __attribute__((ext_vector_type(4))) ushort us4;

// ---------------- scalar convert helpers ----------------
__device__ __forceinline__ ushort f2bf(float x) {      // fp32 -> bf16 (RNE)
    unsigned u = __float_as_uint(x);
    u += 0x7fffu + ((u >> 16) & 1u);
    return (ushort)(u >> 16);
}
__device__ __forceinline__ float bf2f(ushort h) {
    return __uint_as_float((unsigned)h << 16);
}
__device__ __forceinline__ ushort f2h(float x) {       // fp32 -> fp16 bits (RNE)
    union { _Float16 h; ushort u; } cv;
    cv.h = (_Float16)x;
    return cv.u;
}

// async global->LDS, 16B per lane. dst must be wave-uniform base (+lane*16 by HW).
__device__ __forceinline__ void gload_lds16(const void* g, void* s) {
    __builtin_amdgcn_global_load_lds(
        (const __attribute__((address_space(1))) unsigned*)g,
        (__attribute__((address_space(3))) unsigned*)s, 16, 0, 0);
}

// ---------------- fp16 MFMA GEMM + fused attention coefficients ----------
// zf8[M,512] = fp8_e4m3(A[M,K] @ B[K,512]);  as/ad[row,head] from fp32 acc
// (exact, pre-quantization).  BM=BN=128, 4 waves, 16x16x32 f16 MFMA.
__global__ __launch_bounds__(256) void k_gemm_f16(
    const ushort* __restrict__ A, const ushort* __restrict__ BT,
    const float* __restrict__ a_srcv, const float* __restrict__ a_dstv,
    unsigned char* __restrict__ Cf8, float* __restrict__ as_b,
    float* __restrict__ ad_b, int M, int K)
{
    __shared__ __align__(16) ushort As[128 * 64];
    __shared__ __align__(16) ushort Bs[128 * 64];
    __shared__ float sred[2][128];

    const int tid = threadIdx.x;
    const int nwg = gridDim.x;
    const int orig = blockIdx.x;
    const int q = nwg >> 3, r = nwg & 7, xcd = orig & 7;
    const int wgid = (xcd < r ? xcd * (q + 1) : r * (q + 1) + (xcd - r) * q) + (orig >> 3);
    const int bm = (wgid >> 2) * 128;
    const int bn = (wgid & 3) * 128;

    const int l = tid & 63;
    const int w = tid >> 6;
    const int wm = (w >> 1) * 64, wn = (w & 1) * 64;
    const int fr = l & 15;
    const int fk = (l >> 4) * 8;

    if (tid < 128) { sred[0][tid] = 0.f; sred[1][tid] = 0.f; }

    f32x4 zero = {0.f, 0.f, 0.f, 0.f};
    f32x4 acc[4][4];
#pragma unroll
    for (int m = 0; m < 4; ++m)
#pragma unroll
        for (int n = 0; n < 4; ++n) acc[m][n] = zero;

    const int nsteps = K >> 6;
    const int wbase = (tid & 0xC0) << 4;       // wave-uniform byte base

    for (int ks = 0; ks < nsteps; ++ks) {
        int k0 = ks << 6;
#pragma unroll
        for (int i = 0; i < 4; ++i) {
            int c = i * 256 + tid;
            int row = c >> 3;
            int col16 = (c & 7) ^ (row & 7);
            int arow = bm + row; arow = arow < M ? arow : M - 1;
            gload_lds16(A + (size_t)arow * K + k0 + (col16 << 3),
                        (char*)As + i * 4096 + wbase);
        }
#pragma unroll
        for (int i = 0; i < 4; ++i) {
            int c = i * 256 + tid;
            int j = c >> 3;
            int col16 = (c & 7) ^ (j & 7);
            gload_lds16(BT + (size_t)(bn + j) * K + k0 + (col16 << 3),
                        (char*)Bs + i * 4096 + wbase);
        }
        __syncthreads();
#pragma unroll
        for (int kk = 0; kk < 64; kk += 32) {
            f16x8 a[4], b[4];
            int kb = (kk + fk) >> 3;
#pragma unroll
            for (int m = 0; m < 4; ++m) {
                int row = wm + m * 16 + fr;
                a[m] = *(const f16x8*)((const char*)As + row * 128 + ((kb ^ (row & 7)) << 4));
            }
#pragma unroll
            for (int n = 0; n < 4; ++n) {
                int col = wn + n * 16 + fr;
                b[n] = *(const f16x8*)((const char*)Bs + col * 128 + ((kb ^ (col & 7)) << 4));
            }
#pragma unroll
            for (int m = 0; m < 4; ++m)
#pragma unroll
                for (int n = 0; n < 4; ++n)
                    acc[m][n] = __builtin_amdgcn_mfma_f32_16x16x32_f16(a[m], b[n], acc[m][n], 0, 0, 0);
        }
        __syncthreads();
    }

    // ---- epilogue: fp8 z mirror + fused as/ad (from exact fp32 acc) ----
    // C/D layout: col = lane&15, row = (lane>>4)*4 + reg
    const int hh = bn >> 7;                    // this block's head
    float asl[4], adl[4];
#pragma unroll
    for (int n = 0; n < 4; ++n) {
        int c = wn + n * 16 + fr;
        asl[n] = a_srcv[hh * 128 + c];
        adl[n] = a_dstv[hh * 128 + c];
    }
    const int rbase = (l >> 4) * 4;
#pragma unroll
    for (int m = 0; m < 4; ++m) {
#pragma unroll
        for (int rr = 0; rr < 4; ++rr) {
            int rloc = wm + m * 16 + rbase + rr;
            int rowi = bm + rloc;
            float ps = 0.f, pd = 0.f;
#pragma unroll
            for (int n = 0; n < 4; ++n) {
                float v = acc[m][n][rr];
                ps += v * asl[n];
                pd += v * adl[n];
                if (rowi < M) {
                    int pk = __builtin_amdgcn_cvt_pk_fp8_f32(v, v, 0, false);
                    Cf8[(size_t)rowi * HC + bn + wn + n * 16 + fr] = (unsigned char)pk;
                }
            }
#pragma unroll
            for (int off = 1; off < 16; off <<= 1) {
                ps += __shfl_xor(ps, off, 64);
                pd += __shfl_xor(pd, off, 64);
            }
            if (fr == 0) {
                atomicAdd(&sred[0][rloc], ps);
                atomicAdd(&sred[1][rloc], pd);
            }
        }
    }
    __syncthreads();
    if (tid < 128) {
        int rowi = bm + tid;
        if (rowi < M) {
            as_b[rowi * 4 + hh] = sred[0][tid];
            ad_b[rowi * 4 + hh] = sred[1][tid];
        }
    }
}

// ---------------- conversions ----------------
__global__ void k_cvt_f16(const float* __restrict__ in, ushort* __restrict__ o,
                          int n4) {
    int i = blockIdx.x * blockDim.x + threadIdx.x;
    if (i >= n4) return;
    float4 v = ((const float4*)in)[i];
    ushort4 h;
    h.x = f2h(v.x); h.y = f2h(v.y); h.z = f2h(v.z); h.w = f2h(v.w);
    ((ushort4*)o)[i] = h;
}

// W[K][512] -> WT[512][K] fp16
__global__ void k_cvt_wT(const float* __restrict__ W, ushort* __restrict__ hT,
                         int K, int logK) {
    int id = blockIdx.x * blockDim.x + threadIdx.x;
    if (id >= (HC << logK)) return;
    int nn = id >> logK, k = id & (K - 1);
    hT[id] = f2h(W[(size_t)k * HC + nn]);
}

// ---------------- CSR build ----------------
__global__ void k_deg(const int* __restrict__ ei, int* __restrict__ deg) {
    int e = blockIdx.x * blockDim.x + threadIdx.x;
    if (e >= NET) return;
    int d = (e < NE) ? ei[NE + e] : (e - NE);
    atomicAdd(&deg[d], 1);
}

__global__ __launch_bounds__(1024) void k_scan(const int* __restrict__ cnt,
                                               int* __restrict__ off, int n) {
    __shared__ int sums[1024];
    const int tid = threadIdx.x;
    const int chunk = (n + 1023) >> 10;
    const int beg = tid * chunk;
    const int end = min(beg + chunk, n);
    int s = 0;
    for (int i = beg; i < end; ++i) s += cnt[i];
    sums[tid] = s;
    __syncthreads();
    for (int d = 1; d < 1024; d <<= 1) {
        int t = (tid >= d) ? sums[tid - d] : 0;
        __syncthreads();
        sums[tid] += t;
        __syncthreads();
    }
    int run = (tid == 0) ? 0 : sums[tid - 1];
    for (int i = beg; i < end; ++i) { off[i] = run; run += cnt[i]; }
    if (tid == 1023) off[n] = sums[1023];
}

__global__ void k_fill(const int* __restrict__ ei,
                       const int* __restrict__ rowptr,
                       int* __restrict__ fillcnt,
                       int* __restrict__ colsrc) {
    int e = blockIdx.x * blockDim.x + threadIdx.x;
    if (e >= NET) return;
    int s, d;
    if (e < NE) { s = ei[e]; d = ei[NE + e]; } else { s = d = e - NE; }
    int pos = rowptr[d] + atomicAdd(&fillcnt[d], 1);
    colsrc[pos] = s;
}

// ---------------- alpha + inverse-denominator precompute ----------------
// Unnormalized softmax (no max pass: |e| <~ 2 by construction, fp32-safe,
// softmax is shift-invariant). alpha edge-major [NET][4]; 4 lanes per node.
__global__ __launch_bounds__(256) void k_stats(
    const float* __restrict__ as, const float* __restrict__ ad,
    const int* __restrict__ rowptr, const int* __restrict__ colsrc,
    float* __restrict__ alpha, float* __restrict__ dinv, int N)
{
    const int n = blockIdx.x * 64 + (threadIdx.x >> 2);
    if (n >= N) return;
    const int h = threadIdx.x & 3;
    const int beg = rowptr[n], end = rowptr[n + 1];
    const float adn = ad[n * 4 + h];
    float sum = 0.f;
    for (int e = beg; e < end; ++e) {
        float ev = as[colsrc[e] * 4 + h] + adn;
        ev = ev > 0.f ? ev : 0.2f * ev;
        float a = __expf(ev);
        alpha[(size_t)e * 4 + h] = a;
        sum += a;
    }
    dinv[n * 4 + h] = 1.0f / (sum + 1e-16f);
}

// ---------------- fp8 weighted gather ----------------
// Block = 256 thr = 8 subgroups of 32 = 4 nodes x 2 heads (same node's two
// heads share a wave -> identical trip counts). 2 head-pair phases -> fp8 z
// working set per phase = 12.8 MB. Inner loop: colsrc + alpha(broadcast) +
// 4B z-uint + hw fp8 decode + FMA. obf16=0: fp16 out; obf16=1: bf16 out.
__global__ __launch_bounds__(256) void k_gather(
    const unsigned char* __restrict__ zf8, const float* __restrict__ alpha,
    const float* __restrict__ dinv, const int* __restrict__ rowptr,
    const int* __restrict__ colsrc, const float* __restrict__ bias,
    ushort* __restrict__ o16, int obf16)
{
    const int npb = NN >> 2;                   // 12500 blocks per phase
    const int hp = blockIdx.x / npb;           // head-pair phase (0,1)
    const int sub = threadIdx.x >> 5;
    const int node = (blockIdx.x % npb) * 4 + (sub >> 1);
    const int head = hp * 2 + (sub & 1);
    const int lane = threadIdx.x & 31;
    const int beg = rowptr[node], end = rowptr[node + 1];
    const unsigned char* __restrict__ zh = zf8 + head * 128 + (lane << 2);

    float ax = 0.f, ay = 0.f, az = 0.f, aw = 0.f;
    int e = beg;
    for (; e + 4 <= end; e += 4) {
        int s0 = colsrc[e], s1 = colsrc[e + 1], s2 = colsrc[e + 2], s3 = colsrc[e + 3];
        float a0 = alpha[(size_t)e * 4 + head];
        float a1 = alpha[(size_t)(e + 1) * 4 + head];
        float a2 = alpha[(size_t)(e + 2) * 4 + head];
        float a3 = alpha[(size_t)(e + 3) * 4 + head];
        unsigned u0 = *(const unsigned*)&zh[(size_t)s0 * HC];
        unsigned u1 = *(const unsigned*)&zh[(size_t)s1 * HC];
        unsigned u2 = *(const unsigned*)&zh[(size_t)s2 * HC];
        unsigned u3 = *(const unsigned*)&zh[(size_t)s3 * HC];
        f32x2 l0 = __builtin_amdgcn_cvt_pk_f32_fp8(u0, false);
        f32x2 h0 = __builtin_amdgcn_cvt_pk_f32_fp8(u0, true);
        f32x2 l1 = __builtin_amdgcn_cvt_pk_f32_fp8(u1, false);
        f32x2 h1 = __builtin_amdgcn_cvt_pk_f32_fp8(u1, true);
        f32x2 l2 = __builtin_amdgcn_cvt_pk_f32_fp8(u2, false);
        f32x2 h2 = __builtin_amdgcn_cvt_pk_f32_fp8(u2, true);
        f32x2 l3 = __builtin_amdgcn_cvt_pk_f32_fp8(u3, false);
        f32x2 h3 = __builtin_amdgcn_cvt_pk_f32_fp8(u3, true);
        ax += a0 * l0.x + a1 * l1.x + a2 * l2.x + a3 * l3.x;
        ay += a0 * l0.y + a1 * l1.y + a2 * l2.y + a3 * l3.y;
        az += a0 * h0.x + a1 * h1.x + a2 * h2.x + a3 * h3.x;
        aw += a0 * h0.y + a1 * h1.y + a2 * h2.y + a3 * h3.y;
    }
    for (; e < end; ++e) {
        int s0 = colsrc[e];
        float a0 = alpha[(size_t)e * 4 + head];
        unsigned u0 = *(const unsigned*)&zh[(size_t)s0 * HC];
        f32x2 l0 = __builtin_amdgcn_cvt_pk_f32_fp8(u0, false);
        f32x2 h0 = __builtin_amdgcn_cvt_pk_f32_fp8(u0, true);
        ax += a0 * l0.x; ay += a0 * l0.y; az += a0 * h0.x; aw += a0 * h0.y;
    }
    const float di = dinv[node * 4 + head];
    const int col = head * 128 + (lane << 2);
    float4 bv = *(const float4*)&bias[col];
    float rx = fmaxf(ax * di + bv.x, 0.f), ry = fmaxf(ay * di + bv.y, 0.f);
    float rz = fmaxf(az * di + bv.z, 0.f), rw = fmaxf(aw * di + bv.w, 0.f);
    us4 h;
    if (obf16) {
        h.x = f2bf(rx); h.y = f2bf(ry); h.z = f2bf(rz); h.w = f2bf(rw);
    } else {
        h.x = f2h(rx); h.y = f2h(ry); h.z = f2h(rz); h.w = f2h(rw);
    }
    __builtin_nontemporal_store(h, (us4*)&o16[(size_t)node * HC + col]);
}

// ---------------- pooling (bf16 input) / classifier ----------------
__global__ void k_gcnt(const int* __restrict__ batch, int* __restrict__ gcnt) {
    int n = blockIdx.x * blockDim.x + threadIdx.x;
    if (n < NN) atomicAdd(&gcnt[batch[n]], 1);
}

__global__ __launch_bounds__(128) void k_pool(const ushort* __restrict__ h,
                                              const int* __restrict__ goff,
                                              const int* __restrict__ gcnt,
                                              float* __restrict__ hg) {
    const int g = blockIdx.x;
    const int tid = threadIdx.x;
    const int beg = goff[g];
    const int cnt = gcnt[g];
    float4 acc = make_float4(0.f, 0.f, 0.f, 0.f);
    for (int r = beg; r < beg + cnt; ++r) {
        ushort4 v = *(const ushort4*)&h[(size_t)r * HC + (tid << 2)];
        acc.x += bf2f(v.x); acc.y += bf2f(v.y);
        acc.z += bf2f(v.z); acc.w += bf2f(v.w);
    }
    float inv = 1.0f / (float)max(cnt, 1);
    *(float4*)&hg[(size_t)g * HC + (tid << 2)] =
        make_float4(acc.x * inv, acc.y * inv, acc.z * inv, acc.w * inv);
}

__global__ __launch_bounds__(64) void k_cls(const float* __restrict__ hg,
                                            const float* __restrict__ Wc,
                                            const float* __restrict__ bc,
                                            float* __restrict__ out) {
    const int g = blockIdx.x;
    const int lane = threadIdx.x;
#pragma unroll 1
    for (int cls = 0; cls < NCLS; ++cls) {
        float p = 0.f;
#pragma unroll
        for (int j = 0; j < 8; ++j) {
            int c = lane + j * 64;
            p += hg[(size_t)g * HC + c] * Wc[c * NCLS + cls];
        }
#pragma unroll
        for (int off = 32; off; off >>= 1) p += __shfl_down(p, off, 64);
        if (lane == 0) out[g * NCLS + cls] = p + bc[cls];
    }
}

// ---------------- launch ----------------
extern "C" void kernel_launch(void* const* d_in, const int* in_sizes, int n_in,
                              void* d_out, int out_size, void* d_ws, size_t ws_size,
                              hipStream_t stream) {
    const float* x     = (const float*)d_in[0];
    const int*   ei    = (const int*)d_in[1];
    const int*   batch = (const int*)d_in[2];
    const float* W1    = (const float*)d_in[3];
    const float* asrc1 = (const float*)d_in[4];
    const float* adst1 = (const float*)d_in[5];
    const float* b1    = (const float*)d_in[6];
    const float* W2    = (const float*)d_in[7];
    const float* asrc2 = (const float*)d_in[8];
    const float* adst2 = (const float*)d_in[9];
    const float* b2    = (const float*)d_in[10];
    const float* Wc    = (const float*)d_in[11];
    const float* bc    = (const float*)d_in[12];
    float* out = (float*)d_out;
    (void)in_sizes; (void)n_in; (void)out_size; (void)ws_size;

    // ---- region plan (sequential lifetimes on stream):
    // A @0      (25.6 MB): zf8 (fp8 z mirror, both layers)
    // B @25.6M  (51.2 MB): xf16 25.6 [cvt..GEMM1] -> h1f16 51.2 [gather1..GEMM2]
    //                      -> h2b 51.2 [gather2..pool]
    char* R = (char*)d_ws;
    const size_t MB512 = (size_t)NN * HC;        // 25.6M elements
    unsigned char* zf8 = (unsigned char*)R;
    ushort* xf16  = (ushort*)(R + MB512);
    ushort* h1f16 = (ushort*)(R + MB512);
    ushort* h2b   = (ushort*)(R + MB512);

    char* w = R + MB512 * 3;
    size_t off = 0;
    auto alloc = [&](size_t bytes) {
        void* p = w + off;
        off += (bytes + 255) & ~(size_t)255;
        return p;
    };
    float* as_b = (float*)alloc((size_t)NN * NH * 4);
    float* ad_b = (float*)alloc((size_t)NN * NH * 4);
    float* dinv = (float*)alloc((size_t)NN * NH * 4);
    int* rowptr = (int*)alloc((size_t)(NN + 1) * 4);
    int* deg    = (int*)alloc((size_t)NN * 4);
    int* colsrc = (int*)alloc((size_t)NET * 4);
    int* gcnt   = (int*)alloc((size_t)NG * 4);
    int* goff   = (int*)alloc((size_t)(NG + 1) * 4);
    float* hg   = (float*)alloc((size_t)NG * HC * 4);
    ushort* W1T = (ushort*)alloc((size_t)HC * IND * 2);
    ushort* W2T = (ushort*)alloc((size_t)HC * HC * 2);
    float* alpha = (float*)alloc((size_t)NET * NH * 4);  // edge-major [NET][4]

    const int EB = 256, EG = (NET + EB - 1) / EB;
    const int MT = (NN + 127) / 128;
    const int GG = 2 * (NN >> 2);                // 2 head-pair phases

    // ---- conversions ----
    k_cvt_f16<<<(NN * IND / 4 + 255) / 256, 256, 0, stream>>>(x, xf16, NN * IND / 4);
    k_cvt_wT<<<(HC * IND + 255) / 256, 256, 0, stream>>>(W1, W1T, IND, 8);
    k_cvt_wT<<<(HC * HC + 255) / 256, 256, 0, stream>>>(W2, W2T, HC, 9);

    // ---- CSR build ----
    hipMemsetAsync(deg, 0, (size_t)NN * 4, stream);
    k_deg<<<EG, EB, 0, stream>>>(ei, deg);
    k_scan<<<1, 1024, 0, stream>>>(deg, rowptr, NN);
    hipMemsetAsync(deg, 0, (size_t)NN * 4, stream);
    k_fill<<<EG, EB, 0, stream>>>(ei, rowptr, deg, colsrc);

    // ---- graph offsets ----
    hipMemsetAsync(gcnt, 0, (size_t)NG * 4, stream);
    k_gcnt<<<(NN + 255) / 256, 256, 0, stream>>>(batch, gcnt);
    k_scan<<<1, 1024, 0, stream>>>(gcnt, goff, NG);

    // ================= layer 1 =================
    k_gemm_f16<<<MT * 4, 256, 0, stream>>>(xf16, W1T, asrc1, adst1,
                                           zf8, as_b, ad_b, NN, IND);
    k_stats<<<(NN + 63) / 64, 256, 0, stream>>>(as_b, ad_b, rowptr, colsrc,
                                                alpha, dinv, NN);
    k_gather<<<GG, 256, 0, stream>>>(zf8, alpha, dinv, rowptr, colsrc, b1,
                                     h1f16, 0);

    // ================= layer 2 =================
    k_gemm_f16<<<MT * 4, 256, 0, stream>>>(h1f16, W2T, asrc2, adst2,
                                           zf8, as_b, ad_b, NN, HC);
    k_stats<<<(NN + 63) / 64, 256, 0, stream>>>(as_b, ad_b, rowptr, colsrc,
                                                alpha, dinv, NN);
    k_gather<<<GG, 256, 0, stream>>>(zf8, alpha, dinv, rowptr, colsrc, b2,
                                     h2b, 1);

    // ================= pool + classify =================
    k_pool<<<NG, 128, 0, stream>>>(h2b, goff, gcnt, hg);
    k_cls<<<NG, 64, 0, stream>>>(hg, Wc, bc, out);
}

// Round 10
// 418.783 us; speedup vs baseline: 1.2469x; 1.1453x over previous
//
#include <hip/hip_runtime.h>

// ---------------- problem constants ----------------
#define NN      50000      // nodes
#define NE      500000     // edges (before self loops)
#define NET     550000     // edges + self loops
#define IND     256        // input dim
#define HC      512        // heads*hidden
#define NH      4          // heads
#define NG      512        // graphs
#define NCLS    10

typedef __attribute__((ext_vector_type(8))) _Float16 f16x8;
typedef __attribute__((ext_vector_type(4))) float f32x4;
typedef __attribute__((ext_vector_type(2))) float f32x2;
typedef __attribute__((ext_vector_type(4))) ushort us4;

// ---------------- scalar convert helpers ----------------
__device__ __forceinline__ ushort f2bf(float x) {      // fp32 -> bf16 (RNE)
    unsigned u = __float_as_uint(x);
    u += 0x7fffu + ((u >> 16) & 1u);
    return (ushort)(u >> 16);
}
__device__ __forceinline__ float bf2f(ushort h) {
    return __uint_as_float((unsigned)h << 16);
}
__device__ __forceinline__ ushort f2h(float x) {       // fp32 -> fp16 bits (RNE)
    union { _Float16 h; ushort u; } cv;
    cv.h = (_Float16)x;
    return cv.u;
}

// async global->LDS, 16B per lane. dst must be wave-uniform base (+lane*16 by HW).
__device__ __forceinline__ void gload_lds16(const void* g, void* s) {
    __builtin_amdgcn_global_load_lds(
        (const __attribute__((address_space(1))) unsigned*)g,
        (__attribute__((address_space(3))) unsigned*)s, 16, 0, 0);
}

// ---------------- fp16 MFMA GEMM + fused attention coefficients ----------
// zf8[M,512] = fp8_e4m3(A[M,K] @ B[K,512]);  as/ad[row,head] from fp32 acc
// (exact, pre-quantization).  BM=BN=128, 4 waves, 16x16x32 f16 MFMA.
__global__ __launch_bounds__(256) void k_gemm_f16(
    const ushort* __restrict__ A, const ushort* __restrict__ BT,
    const float* __restrict__ a_srcv, const float* __restrict__ a_dstv,
    unsigned char* __restrict__ Cf8, float* __restrict__ as_b,
    float* __restrict__ ad_b, int M, int K)
{
    __shared__ __align__(16) ushort As[128 * 64];
    __shared__ __align__(16) ushort Bs[128 * 64];
    __shared__ float sred[2][128];

    const int tid = threadIdx.x;
    const int nwg = gridDim.x;
    const int orig = blockIdx.x;
    const int q = nwg >> 3, r = nwg & 7, xcd = orig & 7;
    const int wgid = (xcd < r ? xcd * (q + 1) : r * (q + 1) + (xcd - r) * q) + (orig >> 3);
    const int bm = (wgid >> 2) * 128;
    const int bn = (wgid & 3) * 128;

    const int l = tid & 63;
    const int w = tid >> 6;
    const int wm = (w >> 1) * 64, wn = (w & 1) * 64;
    const int fr = l & 15;
    const int fk = (l >> 4) * 8;

    if (tid < 128) { sred[0][tid] = 0.f; sred[1][tid] = 0.f; }

    f32x4 zero = {0.f, 0.f, 0.f, 0.f};
    f32x4 acc[4][4];
#pragma unroll
    for (int m = 0; m < 4; ++m)
#pragma unroll
        for (int n = 0; n < 4; ++n) acc[m][n] = zero;

    const int nsteps = K >> 6;
    const int wbase = (tid & 0xC0) << 4;       // wave-uniform byte base

    for (int ks = 0; ks < nsteps; ++ks) {
        int k0 = ks << 6;
#pragma unroll
        for (int i = 0; i < 4; ++i) {
            int c = i * 256 + tid;
            int row = c >> 3;
            int col16 = (c & 7) ^ (row & 7);
            int arow = bm + row; arow = arow < M ? arow : M - 1;
            gload_lds16(A + (size_t)arow * K + k0 + (col16 << 3),
                        (char*)As + i * 4096 + wbase);
        }
#pragma unroll
        for (int i = 0; i < 4; ++i) {
            int c = i * 256 + tid;
            int j = c >> 3;
            int col16 = (c & 7) ^ (j & 7);
            gload_lds16(BT + (size_t)(bn + j) * K + k0 + (col16 << 3),
                        (char*)Bs + i * 4096 + wbase);
        }
        __syncthreads();
#pragma unroll
        for (int kk = 0; kk < 64; kk += 32) {
            f16x8 a[4], b[4];
            int kb = (kk + fk) >> 3;
#pragma unroll
            for (int m = 0; m < 4; ++m) {
                int row = wm + m * 16 + fr;
                a[m] = *(const f16x8*)((const char*)As + row * 128 + ((kb ^ (row & 7)) << 4));
            }
#pragma unroll
            for (int n = 0; n < 4; ++n) {
                int col = wn + n * 16 + fr;
                b[n] = *(const f16x8*)((const char*)Bs + col * 128 + ((kb ^ (col & 7)) << 4));
            }
#pragma unroll
            for (int m = 0; m < 4; ++m)
#pragma unroll
                for (int n = 0; n < 4; ++n)
                    acc[m][n] = __builtin_amdgcn_mfma_f32_16x16x32_f16(a[m], b[n], acc[m][n], 0, 0, 0);
        }
        __syncthreads();
    }

    // ---- epilogue: fp8 z mirror + fused as/ad (from exact fp32 acc) ----
    // C/D layout: col = lane&15, row = (lane>>4)*4 + reg
    const int hh = bn >> 7;                    // this block's head
    float asl[4], adl[4];
#pragma unroll
    for (int n = 0; n < 4; ++n) {
        int c = wn + n * 16 + fr;
        asl[n] = a_srcv[hh * 128 + c];
        adl[n] = a_dstv[hh * 128 + c];
    }
    const int rbase = (l >> 4) * 4;
#pragma unroll
    for (int m = 0; m < 4; ++m) {
#pragma unroll
        for (int rr = 0; rr < 4; ++rr) {
            int rloc = wm + m * 16 + rbase + rr;
            int rowi = bm + rloc;
            float ps = 0.f, pd = 0.f;
#pragma unroll
            for (int n = 0; n < 4; ++n) {
                float v = acc[m][n][rr];
                ps += v * asl[n];
                pd += v * adl[n];
                if (rowi < M) {
                    int pk = __builtin_amdgcn_cvt_pk_fp8_f32(v, v, 0, false);
                    Cf8[(size_t)rowi * HC + bn + wn + n * 16 + fr] = (unsigned char)pk;
                }
            }
#pragma unroll
            for (int off = 1; off < 16; off <<= 1) {
                ps += __shfl_xor(ps, off, 64);
                pd += __shfl_xor(pd, off, 64);
            }
            if (fr == 0) {
                atomicAdd(&sred[0][rloc], ps);
                atomicAdd(&sred[1][rloc], pd);
            }
        }
    }
    __syncthreads();
    if (tid < 128) {
        int rowi = bm + tid;
        if (rowi < M) {
            as_b[rowi * 4 + hh] = sred[0][tid];
            ad_b[rowi * 4 + hh] = sred[1][tid];
        }
    }
}

// ---------------- conversions ----------------
__global__ void k_cvt_f16(const float* __restrict__ in, ushort* __restrict__ o,
                          int n4) {
    int i = blockIdx.x * blockDim.x + threadIdx.x;
    if (i >= n4) return;
    float4 v = ((const float4*)in)[i];
    ushort4 h;
    h.x = f2h(v.x); h.y = f2h(v.y); h.z = f2h(v.z); h.w = f2h(v.w);
    ((ushort4*)o)[i] = h;
}

// W[K][512] -> WT[512][K] fp16
__global__ void k_cvt_wT(const float* __restrict__ W, ushort* __restrict__ hT,
                         int K, int logK) {
    int id = blockIdx.x * blockDim.x + threadIdx.x;
    if (id >= (HC << logK)) return;
    int nn = id >> logK, k = id & (K - 1);
    hT[id] = f2h(W[(size_t)k * HC + nn]);
}

// ---------------- CSR build ----------------
__global__ void k_deg(const int* __restrict__ ei, int* __restrict__ deg) {
    int e = blockIdx.x * blockDim.x + threadIdx.x;
    if (e >= NET) return;
    int d = (e < NE) ? ei[NE + e] : (e - NE);
    atomicAdd(&deg[d], 1);
}

// ---- hierarchical exclusive scan (3 kernels; supports n up to 256*1024) ----
__global__ __launch_bounds__(256) void k_scan_part(const int* __restrict__ cnt,
                                                   int* __restrict__ bsum, int n) {
    __shared__ int red[256];
    const int tid = threadIdx.x;
    int i = blockIdx.x * 256 + tid;
    red[tid] = (i < n) ? cnt[i] : 0;
    __syncthreads();
#pragma unroll
    for (int d = 128; d; d >>= 1) {
        if (tid < d) red[tid] += red[tid + d];
        __syncthreads();
    }
    if (tid == 0) bsum[blockIdx.x] = red[0];
}

// single block; nb <= 1024. Writes exclusive boff and off[n] = total.
__global__ __launch_bounds__(1024) void k_scan_top(const int* __restrict__ bsum,
                                                   int* __restrict__ boff,
                                                   int* __restrict__ off, int nb, int n) {
    __shared__ int s[1024];
    const int tid = threadIdx.x;
    int v = (tid < nb) ? bsum[tid] : 0;
    s[tid] = v;
    __syncthreads();
    for (int d = 1; d < 1024; d <<= 1) {
        int t = (tid >= d) ? s[tid - d] : 0;
        __syncthreads();
        s[tid] += t;
        __syncthreads();
    }
    if (tid < nb) boff[tid] = s[tid] - v;
    if (tid == nb - 1) off[n] = s[tid];
}

__global__ __launch_bounds__(256) void k_scan_out(const int* __restrict__ cnt,
                                                  const int* __restrict__ boff,
                                                  int* __restrict__ off, int n) {
    __shared__ int s[256];
    const int tid = threadIdx.x;
    int i = blockIdx.x * 256 + tid;
    int v = (i < n) ? cnt[i] : 0;
    s[tid] = v;
    __syncthreads();
    for (int d = 1; d < 256; d <<= 1) {
        int t = (tid >= d) ? s[tid - d] : 0;
        __syncthreads();
        s[tid] += t;
        __syncthreads();
    }
    if (i < n) off[i] = boff[blockIdx.x] + s[tid] - v;
}

__global__ void k_fill(const int* __restrict__ ei,
                       const int* __restrict__ rowptr,
                       int* __restrict__ fillcnt,
                       int* __restrict__ colsrc) {
    int e = blockIdx.x * blockDim.x + threadIdx.x;
    if (e >= NET) return;
    int s, d;
    if (e < NE) { s = ei[e]; d = ei[NE + e]; } else { s = d = e - NE; }
    int pos = rowptr[d] + atomicAdd(&fillcnt[d], 1);
    colsrc[pos] = s;
}

// ---------------- alpha + inverse-denominator precompute ----------------
// Unnormalized softmax (no max pass: |e| <~ 2 by construction, fp32-safe,
// softmax is shift-invariant). alpha edge-major [NET][4]; 4 lanes per node.
__global__ __launch_bounds__(256) void k_stats(
    const float* __restrict__ as, const float* __restrict__ ad,
    const int* __restrict__ rowptr, const int* __restrict__ colsrc,
    float* __restrict__ alpha, float* __restrict__ dinv, int N)
{
    const int n = blockIdx.x * 64 + (threadIdx.x >> 2);
    if (n >= N) return;
    const int h = threadIdx.x & 3;
    const int beg = rowptr[n], end = rowptr[n + 1];
    const float adn = ad[n * 4 + h];
    float sum = 0.f;
    for (int e = beg; e < end; ++e) {
        float ev = as[colsrc[e] * 4 + h] + adn;
        ev = ev > 0.f ? ev : 0.2f * ev;
        float a = __expf(ev);
        alpha[(size_t)e * 4 + h] = a;
        sum += a;
    }
    dinv[n * 4 + h] = 1.0f / (sum + 1e-16f);
}

// ---------------- fp8 weighted gather ----------------
// Block = 256 thr = 8 subgroups of 32 = 4 nodes x 2 heads (same node's two
// heads share a wave -> identical trip counts). 2 head-pair phases -> fp8 z
// working set per phase = 12.8 MB. obf16=0: fp16 out; obf16=1: bf16 out.
__global__ __launch_bounds__(256) void k_gather(
    const unsigned char* __restrict__ zf8, const float* __restrict__ alpha,
    const float* __restrict__ dinv, const int* __restrict__ rowptr,
    const int* __restrict__ colsrc, const float* __restrict__ bias,
    ushort* __restrict__ o16, int obf16)
{
    const int npb = NN >> 2;                   // 12500 blocks per phase
    const int hp = blockIdx.x / npb;           // head-pair phase (0,1)
    const int sub = threadIdx.x >> 5;
    const int node = (blockIdx.x % npb) * 4 + (sub >> 1);
    const int head = hp * 2 + (sub & 1);
    const int lane = threadIdx.x & 31;
    const int beg = rowptr[node], end = rowptr[node + 1];
    const unsigned char* __restrict__ zh = zf8 + head * 128 + (lane << 2);

    float ax = 0.f, ay = 0.f, az = 0.f, aw = 0.f;
    int e = beg;
    for (; e + 4 <= end; e += 4) {
        int s0 = colsrc[e], s1 = colsrc[e + 1], s2 = colsrc[e + 2], s3 = colsrc[e + 3];
        float a0 = alpha[(size_t)e * 4 + head];
        float a1 = alpha[(size_t)(e + 1) * 4 + head];
        float a2 = alpha[(size_t)(e + 2) * 4 + head];
        float a3 = alpha[(size_t)(e + 3) * 4 + head];
        unsigned u0 = *(const unsigned*)&zh[(size_t)s0 * HC];
        unsigned u1 = *(const unsigned*)&zh[(size_t)s1 * HC];
        unsigned u2 = *(const unsigned*)&zh[(size_t)s2 * HC];
        unsigned u3 = *(const unsigned*)&zh[(size_t)s3 * HC];
        f32x2 l0 = __builtin_amdgcn_cvt_pk_f32_fp8(u0, false);
        f32x2 h0 = __builtin_amdgcn_cvt_pk_f32_fp8(u0, true);
        f32x2 l1 = __builtin_amdgcn_cvt_pk_f32_fp8(u1, false);
        f32x2 h1 = __builtin_amdgcn_cvt_pk_f32_fp8(u1, true);
        f32x2 l2 = __builtin_amdgcn_cvt_pk_f32_fp8(u2, false);
        f32x2 h2 = __builtin_amdgcn_cvt_pk_f32_fp8(u2, true);
        f32x2 l3 = __builtin_amdgcn_cvt_pk_f32_fp8(u3, false);
        f32x2 h3 = __builtin_amdgcn_cvt_pk_f32_fp8(u3, true);
        ax += a0 * l0.x + a1 * l1.x + a2 * l2.x + a3 * l3.x;
        ay += a0 * l0.y + a1 * l1.y + a2 * l2.y + a3 * l3.y;
        az += a0 * h0.x + a1 * h1.x + a2 * h2.x + a3 * h3.x;
        aw += a0 * h0.y + a1 * h1.y + a2 * h2.y + a3 * h3.y;
    }
    for (; e < end; ++e) {
        int s0 = colsrc[e];
        float a0 = alpha[(size_t)e * 4 + head];
        unsigned u0 = *(const unsigned*)&zh[(size_t)s0 * HC];
        f32x2 l0 = __builtin_amdgcn_cvt_pk_f32_fp8(u0, false);
        f32x2 h0 = __builtin_amdgcn_cvt_pk_f32_fp8(u0, true);
        ax += a0 * l0.x; ay += a0 * l0.y; az += a0 * h0.x; aw += a0 * h0.y;
    }
    const float di = dinv[node * 4 + head];
    const int col = head * 128 + (lane << 2);
    float4 bv = *(const float4*)&bias[col];
    float rx = fmaxf(ax * di + bv.x, 0.f), ry = fmaxf(ay * di + bv.y, 0.f);
    float rz = fmaxf(az * di + bv.z, 0.f), rw = fmaxf(aw * di + bv.w, 0.f);
    us4 h;
    if (obf16) {
        h.x = f2bf(rx); h.y = f2bf(ry); h.z = f2bf(rz); h.w = f2bf(rw);
    } else {
        h.x = f2h(rx); h.y = f2h(ry); h.z = f2h(rz); h.w = f2h(rw);
    }
    __builtin_nontemporal_store(h, (us4*)&o16[(size_t)node * HC + col]);
}

// ---------------- pooling (bf16 input) / classifier ----------------
__global__ void k_gcnt(const int* __restrict__ batch, int* __restrict__ gcnt) {
    int n = blockIdx.x * blockDim.x + threadIdx.x;
    if (n < NN) atomicAdd(&gcnt[batch[n]], 1);
}

__global__ __launch_bounds__(128) void k_pool(const ushort* __restrict__ h,
                                              const int* __restrict__ goff,
                                              const int* __restrict__ gcnt,
                                              float* __restrict__ hg) {
    const int g = blockIdx.x;
    const int tid = threadIdx.x;
    const int beg = goff[g];
    const int cnt = gcnt[g];
    float4 acc = make_float4(0.f, 0.f, 0.f, 0.f);
    for (int r = beg; r < beg + cnt; ++r) {
        ushort4 v = *(const ushort4*)&h[(size_t)r * HC + (tid << 2)];
        acc.x += bf2f(v.x); acc.y += bf2f(v.y);
        acc.z += bf2f(v.z); acc.w += bf2f(v.w);
    }
    float inv = 1.0f / (float)max(cnt, 1);
    *(float4*)&hg[(size_t)g * HC + (tid << 2)] =
        make_float4(acc.x * inv, acc.y * inv, acc.z * inv, acc.w * inv);
}

__global__ __launch_bounds__(64) void k_cls(const float* __restrict__ hg,
                                            const float* __restrict__ Wc,
                                            const float* __restrict__ bc,
                                            float* __restrict__ out) {
    const int g = blockIdx.x;
    const int lane = threadIdx.x;
#pragma unroll 1
    for (int cls = 0; cls < NCLS; ++cls) {
        float p = 0.f;
#pragma unroll
        for (int j = 0; j < 8; ++j) {
            int c = lane + j * 64;
            p += hg[(size_t)g * HC + c] * Wc[c * NCLS + cls];
        }
#pragma unroll
        for (int off = 32; off; off >>= 1) p += __shfl_down(p, off, 64);
        if (lane == 0) out[g * NCLS + cls] = p + bc[cls];
    }
}

// ---------------- launch ----------------
extern "C" void kernel_launch(void* const* d_in, const int* in_sizes, int n_in,
                              void* d_out, int out_size, void* d_ws, size_t ws_size,
                              hipStream_t stream) {
    const float* x     = (const float*)d_in[0];
    const int*   ei    = (const int*)d_in[1];
    const int*   batch = (const int*)d_in[2];
    const float* W1    = (const float*)d_in[3];
    const float* asrc1 = (const float*)d_in[4];
    const float* adst1 = (const float*)d_in[5];
    const float* b1    = (const float*)d_in[6];
    const float* W2    = (const float*)d_in[7];
    const float* asrc2 = (const float*)d_in[8];
    const float* adst2 = (const float*)d_in[9];
    const float* b2    = (const float*)d_in[10];
    const float* Wc    = (const float*)d_in[11];
    const float* bc    = (const float*)d_in[12];
    float* out = (float*)d_out;
    (void)in_sizes; (void)n_in; (void)out_size; (void)ws_size;

    // ---- region plan (sequential lifetimes on stream):
    // A @0      (25.6 MB): zf8 (fp8 z mirror, both layers)
    // B @25.6M  (51.2 MB): xf16 25.6 [cvt..GEMM1] -> h1f16 51.2 [gather1..GEMM2]
    //                      -> h2b 51.2 [gather2..pool]
    char* R = (char*)d_ws;
    const size_t MB512 = (size_t)NN * HC;        // 25.6M elements
    unsigned char* zf8 = (unsigned char*)R;
    ushort* xf16  = (ushort*)(R + MB512);
    ushort* h1f16 = (ushort*)(R + MB512);
    ushort* h2b   = (ushort*)(R + MB512);

    char* w = R + MB512 * 3;
    size_t off = 0;
    auto alloc = [&](size_t bytes) {
        void* p = w + off;
        off += (bytes + 255) & ~(size_t)255;
        return p;
    };
    float* as_b = (float*)alloc((size_t)NN * NH * 4);
    float* ad_b = (float*)alloc((size_t)NN * NH * 4);
    float* dinv = (float*)alloc((size_t)NN * NH * 4);
    int* rowptr = (int*)alloc((size_t)(NN + 1) * 4);
    int* deg    = (int*)alloc((size_t)NN * 4);
    int* colsrc = (int*)alloc((size_t)NET * 4);
    int* gcnt   = (int*)alloc((size_t)NG * 4);
    int* goff   = (int*)alloc((size_t)(NG + 1) * 4);
    int* bsum   = (int*)alloc((size_t)1024 * 4);
    int* boff   = (int*)alloc((size_t)1024 * 4);
    float* hg   = (float*)alloc((size_t)NG * HC * 4);
    ushort* W1T = (ushort*)alloc((size_t)HC * IND * 2);
    ushort* W2T = (ushort*)alloc((size_t)HC * HC * 2);
    float* alpha = (float*)alloc((size_t)NET * NH * 4);  // edge-major [NET][4]

    const int EB = 256, EG = (NET + EB - 1) / EB;
    const int MT = (NN + 127) / 128;
    const int GG = 2 * (NN >> 2);                // 2 head-pair phases
    const int NB_N = (NN + 255) / 256;           // 196 scan blocks (nodes)
    const int NB_G = (NG + 255) / 256;           // 2 scan blocks (graphs)

    // ---- conversions ----
    k_cvt_f16<<<(NN * IND / 4 + 255) / 256, 256, 0, stream>>>(x, xf16, NN * IND / 4);
    k_cvt_wT<<<(HC * IND + 255) / 256, 256, 0, stream>>>(W1, W1T, IND, 8);
    k_cvt_wT<<<(HC * HC + 255) / 256, 256, 0, stream>>>(W2, W2T, HC, 9);

    // ---- CSR build (hierarchical scan) ----
    hipMemsetAsync(deg, 0, (size_t)NN * 4, stream);
    k_deg<<<EG, EB, 0, stream>>>(ei, deg);
    k_scan_part<<<NB_N, 256, 0, stream>>>(deg, bsum, NN);
    k_scan_top<<<1, 1024, 0, stream>>>(bsum, boff, rowptr, NB_N, NN);
    k_scan_out<<<NB_N, 256, 0, stream>>>(deg, boff, rowptr, NN);
    hipMemsetAsync(deg, 0, (size_t)NN * 4, stream);
    k_fill<<<EG, EB, 0, stream>>>(ei, rowptr, deg, colsrc);

    // ---- graph offsets ----
    hipMemsetAsync(gcnt, 0, (size_t)NG * 4, stream);
    k_gcnt<<<(NN + 255) / 256, 256, 0, stream>>>(batch, gcnt);
    k_scan_part<<<NB_G, 256, 0, stream>>>(gcnt, bsum, NG);
    k_scan_top<<<1, 1024, 0, stream>>>(bsum, boff, goff, NB_G, NG);
    k_scan_out<<<NB_G, 256, 0, stream>>>(gcnt, boff, goff, NG);

    // ================= layer 1 =================
    k_gemm_f16<<<MT * 4, 256, 0, stream>>>(xf16, W1T, asrc1, adst1,
                                           zf8, as_b, ad_b, NN, IND);
    k_stats<<<(NN + 63) / 64, 256, 0, stream>>>(as_b, ad_b, rowptr, colsrc,
                                                alpha, dinv, NN);
    k_gather<<<GG, 256, 0, stream>>>(zf8, alpha, dinv, rowptr, colsrc, b1,
                                     h1f16, 0);

    // ================= layer 2 =================
    k_gemm_f16<<<MT * 4, 256, 0, stream>>>(h1f16, W2T, asrc2, adst2,
                                           zf8, as_b, ad_b, NN, HC);
    k_stats<<<(NN + 63) / 64, 256, 0, stream>>>(as_b, ad_b, rowptr, colsrc,
                                                alpha, dinv, NN);
    k_gather<<<GG, 256, 0, stream>>>(zf8, alpha, dinv, rowptr, colsrc, b2,
                                     h2b, 1);

    // ================= pool + classify =================
    k_pool<<<NG, 128, 0, stream>>>(h2b, goff, gcnt, hg);
    k_cls<<<NG, 64, 0, stream>>>(hg, Wc, bc, out);
}

// Round 11
// 408.192 us; speedup vs baseline: 1.2792x; 1.0259x over previous
//
#include <hip/hip_runtime.h>

// ---------------- problem constants ----------------
#define NN      50000      // nodes
#define NE      500000     // edges (before self loops)
#define NET     550000     // edges + self loops
#define IND     256        // input dim
#define HC      512        // heads*hidden
#define NH      4          // heads
#define NG      512        // graphs
#define NCLS    10

typedef __attribute__((ext_vector_type(8))) _Float16 f16x8;
typedef __attribute__((ext_vector_type(4))) float f32x4;
typedef __attribute__((ext_vector_type(2))) float f32x2;
typedef __attribute__((ext_vector_type(4))) ushort us4;

// ---------------- scalar convert helpers ----------------
__device__ __forceinline__ ushort f2bf(float x) {      // fp32 -> bf16 (RNE)
    unsigned u = __float_as_uint(x);
    u += 0x7fffu + ((u >> 16) & 1u);
    return (ushort)(u >> 16);
}
__device__ __forceinline__ float bf2f(ushort h) {
    return __uint_as_float((unsigned)h << 16);
}
__device__ __forceinline__ ushort f2h(float x) {       // fp32 -> fp16 bits (RNE)
    union { _Float16 h; ushort u; } cv;
    cv.h = (_Float16)x;
    return cv.u;
}

// async global->LDS, 16B per lane. dst must be wave-uniform base (+lane*16 by HW).
__device__ __forceinline__ void gload_lds16(const void* g, void* s) {
    __builtin_amdgcn_global_load_lds(
        (const __attribute__((address_space(1))) unsigned*)g,
        (__attribute__((address_space(3))) unsigned*)s, 16, 0, 0);
}

// ---------------- fp16 MFMA GEMM + fused attention coefficients ----------
// zf8[M,512] = fp8_e4m3(A[M,K] @ B[K,512]);  as/ad[row,head] from fp32 acc
// (exact, pre-quantization).
// BM=64, BN=128, BK=64; 256 thr = 4 waves (2x2 of 32x64); LDS 24.5 KB ->
// 6 blocks/CU (vs 4 at BM=128): more resident waves hide the per-K-step
// stage->barrier latency chain. 16x16x32 f16 MFMA.
__global__ __launch_bounds__(256) void k_gemm_f16(
    const ushort* __restrict__ A, const ushort* __restrict__ BT,
    const float* __restrict__ a_srcv, const float* __restrict__ a_dstv,
    unsigned char* __restrict__ Cf8, float* __restrict__ as_b,
    float* __restrict__ ad_b, int M, int K)
{
    __shared__ __align__(16) ushort As[64 * 64];     // 8 KB
    __shared__ __align__(16) ushort Bs[128 * 64];    // 16 KB
    __shared__ float sred[2][64];                    // 0.5 KB

    const int tid = threadIdx.x;
    const int nwg = gridDim.x;                       // 3128, divisible by 8
    const int orig = blockIdx.x;
    const int q = nwg >> 3, r = nwg & 7, xcd = orig & 7;
    const int wgid = (xcd < r ? xcd * (q + 1) : r * (q + 1) + (xcd - r) * q) + (orig >> 3);
    const int bm = (wgid >> 2) * 64;
    const int bn = (wgid & 3) * 128;

    const int l = tid & 63;
    const int w = tid >> 6;
    const int wm = (w >> 1) * 32, wn = (w & 1) * 64;
    const int fr = l & 15;
    const int fk = (l >> 4) * 8;

    if (tid < 64) { sred[0][tid] = 0.f; sred[1][tid] = 0.f; }

    f32x4 zero = {0.f, 0.f, 0.f, 0.f};
    f32x4 acc[2][4];
#pragma unroll
    for (int m = 0; m < 2; ++m)
#pragma unroll
        for (int n = 0; n < 4; ++n) acc[m][n] = zero;

    const int nsteps = K >> 6;
    const int wbase = (tid & 0xC0) << 4;       // wave-uniform byte base

    for (int ks = 0; ks < nsteps; ++ks) {
        int k0 = ks << 6;
        // A tile 64x64 fp16 (8 KB): 2 x 16B chunks per thread
#pragma unroll
        for (int i = 0; i < 2; ++i) {
            int c = i * 256 + tid;
            int row = c >> 3;
            int col16 = (c & 7) ^ (row & 7);
            int arow = bm + row; arow = arow < M ? arow : M - 1;
            gload_lds16(A + (size_t)arow * K + k0 + (col16 << 3),
                        (char*)As + i * 4096 + wbase);
        }
        // B tile 128x64 fp16 (16 KB): 4 x 16B chunks per thread
#pragma unroll
        for (int i = 0; i < 4; ++i) {
            int c = i * 256 + tid;
            int j = c >> 3;
            int col16 = (c & 7) ^ (j & 7);
            gload_lds16(BT + (size_t)(bn + j) * K + k0 + (col16 << 3),
                        (char*)Bs + i * 4096 + wbase);
        }
        __syncthreads();
#pragma unroll
        for (int kk = 0; kk < 64; kk += 32) {
            f16x8 a[2], b[4];
            int kb = (kk + fk) >> 3;
#pragma unroll
            for (int m = 0; m < 2; ++m) {
                int row = wm + m * 16 + fr;
                a[m] = *(const f16x8*)((const char*)As + row * 128 + ((kb ^ (row & 7)) << 4));
            }
#pragma unroll
            for (int n = 0; n < 4; ++n) {
                int col = wn + n * 16 + fr;
                b[n] = *(const f16x8*)((const char*)Bs + col * 128 + ((kb ^ (col & 7)) << 4));
            }
#pragma unroll
            for (int m = 0; m < 2; ++m)
#pragma unroll
                for (int n = 0; n < 4; ++n)
                    acc[m][n] = __builtin_amdgcn_mfma_f32_16x16x32_f16(a[m], b[n], acc[m][n], 0, 0, 0);
        }
        __syncthreads();
    }

    // ---- epilogue: fp8 z mirror + fused as/ad (from exact fp32 acc) ----
    // C/D layout: col = lane&15, row = (lane>>4)*4 + reg
    const int hh = bn >> 7;                    // this block's head
    float asl[4], adl[4];
#pragma unroll
    for (int n = 0; n < 4; ++n) {
        int c = wn + n * 16 + fr;
        asl[n] = a_srcv[hh * 128 + c];
        adl[n] = a_dstv[hh * 128 + c];
    }
    const int rbase = (l >> 4) * 4;
#pragma unroll
    for (int m = 0; m < 2; ++m) {
#pragma unroll
        for (int rr = 0; rr < 4; ++rr) {
            int rloc = wm + m * 16 + rbase + rr;
            int rowi = bm + rloc;
            float ps = 0.f, pd = 0.f;
#pragma unroll
            for (int n = 0; n < 4; ++n) {
                float v = acc[m][n][rr];
                ps += v * asl[n];
                pd += v * adl[n];
                if (rowi < M) {
                    int pk = __builtin_amdgcn_cvt_pk_fp8_f32(v, v, 0, false);
                    Cf8[(size_t)rowi * HC + bn + wn + n * 16 + fr] = (unsigned char)pk;
                }
            }
#pragma unroll
            for (int off = 1; off < 16; off <<= 1) {
                ps += __shfl_xor(ps, off, 64);
                pd += __shfl_xor(pd, off, 64);
            }
            if (fr == 0) {
                atomicAdd(&sred[0][rloc], ps);
                atomicAdd(&sred[1][rloc], pd);
            }
        }
    }
    __syncthreads();
    if (tid < 64) {
        int rowi = bm + tid;
        if (rowi < M) {
            as_b[rowi * 4 + hh] = sred[0][tid];
            ad_b[rowi * 4 + hh] = sred[1][tid];
        }
    }
}

// ---------------- conversions ----------------
__global__ void k_cvt_f16(const float* __restrict__ in, ushort* __restrict__ o,
                          int n4) {
    int i = blockIdx.x * blockDim.x + threadIdx.x;
    if (i >= n4) return;
    float4 v = ((const float4*)in)[i];
    ushort4 h;
    h.x = f2h(v.x); h.y = f2h(v.y); h.z = f2h(v.z); h.w = f2h(v.w);
    ((ushort4*)o)[i] = h;
}

// W[K][512] -> WT[512][K] fp16
__global__ void k_cvt_wT(const float* __restrict__ W, ushort* __restrict__ hT,
                         int K, int logK) {
    int id = blockIdx.x * blockDim.x + threadIdx.x;
    if (id >= (HC << logK)) return;
    int nn = id >> logK, k = id & (K - 1);
    hT[id] = f2h(W[(size_t)k * HC + nn]);
}

// ---------------- CSR build ----------------
__global__ void k_deg(const int* __restrict__ ei, int* __restrict__ deg) {
    int e = blockIdx.x * blockDim.x + threadIdx.x;
    if (e >= NET) return;
    int d = (e < NE) ? ei[NE + e] : (e - NE);
    atomicAdd(&deg[d], 1);
}

// ---- hierarchical exclusive scan (3 kernels; supports n up to 256*1024) ----
__global__ __launch_bounds__(256) void k_scan_part(const int* __restrict__ cnt,
                                                   int* __restrict__ bsum, int n) {
    __shared__ int red[256];
    const int tid = threadIdx.x;
    int i = blockIdx.x * 256 + tid;
    red[tid] = (i < n) ? cnt[i] : 0;
    __syncthreads();
#pragma unroll
    for (int d = 128; d; d >>= 1) {
        if (tid < d) red[tid] += red[tid + d];
        __syncthreads();
    }
    if (tid == 0) bsum[blockIdx.x] = red[0];
}

// single block; nb <= 1024. Writes exclusive boff and off[n] = total.
__global__ __launch_bounds__(1024) void k_scan_top(const int* __restrict__ bsum,
                                                   int* __restrict__ boff,
                                                   int* __restrict__ off, int nb, int n) {
    __shared__ int s[1024];
    const int tid = threadIdx.x;
    int v = (tid < nb) ? bsum[tid] : 0;
    s[tid] = v;
    __syncthreads();
    for (int d = 1; d < 1024; d <<= 1) {
        int t = (tid >= d) ? s[tid - d] : 0;
        __syncthreads();
        s[tid] += t;
        __syncthreads();
    }
    if (tid < nb) boff[tid] = s[tid] - v;
    if (tid == nb - 1) off[n] = s[tid];
}

__global__ __launch_bounds__(256) void k_scan_out(const int* __restrict__ cnt,
                                                  const int* __restrict__ boff,
                                                  int* __restrict__ off, int n) {
    __shared__ int s[256];
    const int tid = threadIdx.x;
    int i = blockIdx.x * 256 + tid;
    int v = (i < n) ? cnt[i] : 0;
    s[tid] = v;
    __syncthreads();
    for (int d = 1; d < 256; d <<= 1) {
        int t = (tid >= d) ? s[tid - d] : 0;
        __syncthreads();
        s[tid] += t;
        __syncthreads();
    }
    if (i < n) off[i] = boff[blockIdx.x] + s[tid] - v;
}

__global__ void k_fill(const int* __restrict__ ei,
                       const int* __restrict__ rowptr,
                       int* __restrict__ fillcnt,
                       int* __restrict__ colsrc) {
    int e = blockIdx.x * blockDim.x + threadIdx.x;
    if (e >= NET) return;
    int s, d;
    if (e < NE) { s = ei[e]; d = ei[NE + e]; } else { s = d = e - NE; }
    int pos = rowptr[d] + atomicAdd(&fillcnt[d], 1);
    colsrc[pos] = s;
}

// ---------------- alpha + inverse-denominator precompute ----------------
// Unnormalized softmax (no max pass: |e| <~ 2 by construction, fp32-safe,
// softmax is shift-invariant). alpha edge-major [NET][4]; 4 lanes per node.
__global__ __launch_bounds__(256) void k_stats(
    const float* __restrict__ as, const float* __restrict__ ad,
    const int* __restrict__ rowptr, const int* __restrict__ colsrc,
    float* __restrict__ alpha, float* __restrict__ dinv, int N)
{
    const int n = blockIdx.x * 64 + (threadIdx.x >> 2);
    if (n >= N) return;
    const int h = threadIdx.x & 3;
    const int beg = rowptr[n], end = rowptr[n + 1];
    const float adn = ad[n * 4 + h];
    float sum = 0.f;
    for (int e = beg; e < end; ++e) {
        float ev = as[colsrc[e] * 4 + h] + adn;
        ev = ev > 0.f ? ev : 0.2f * ev;
        float a = __expf(ev);
        alpha[(size_t)e * 4 + h] = a;
        sum += a;
    }
    dinv[n * 4 + h] = 1.0f / (sum + 1e-16f);
}

// ---------------- fp8 weighted gather ----------------
// Block = 256 thr = 8 subgroups of 32 = 4 nodes x 2 heads (same node's two
// heads share a wave -> identical trip counts). 2 head-pair phases -> fp8 z
// working set per phase = 12.8 MB. obf16=0: fp16 out; obf16=1: bf16 out.
__global__ __launch_bounds__(256) void k_gather(
    const unsigned char* __restrict__ zf8, const float* __restrict__ alpha,
    const float* __restrict__ dinv, const int* __restrict__ rowptr,
    const int* __restrict__ colsrc, const float* __restrict__ bias,
    ushort* __restrict__ o16, int obf16)
{
    const int npb = NN >> 2;                   // 12500 blocks per phase
    const int hp = blockIdx.x / npb;           // head-pair phase (0,1)
    const int sub = threadIdx.x >> 5;
    const int node = (blockIdx.x % npb) * 4 + (sub >> 1);
    const int head = hp * 2 + (sub & 1);
    const int lane = threadIdx.x & 31;
    const int beg = rowptr[node], end = rowptr[node + 1];
    const unsigned char* __restrict__ zh = zf8 + head * 128 + (lane << 2);

    float ax = 0.f, ay = 0.f, az = 0.f, aw = 0.f;
    int e = beg;
    for (; e + 4 <= end; e += 4) {
        int s0 = colsrc[e], s1 = colsrc[e + 1], s2 = colsrc[e + 2], s3 = colsrc[e + 3];
        float a0 = alpha[(size_t)e * 4 + head];
        float a1 = alpha[(size_t)(e + 1) * 4 + head];
        float a2 = alpha[(size_t)(e + 2) * 4 + head];
        float a3 = alpha[(size_t)(e + 3) * 4 + head];
        unsigned u0 = *(const unsigned*)&zh[(size_t)s0 * HC];
        unsigned u1 = *(const unsigned*)&zh[(size_t)s1 * HC];
        unsigned u2 = *(const unsigned*)&zh[(size_t)s2 * HC];
        unsigned u3 = *(const unsigned*)&zh[(size_t)s3 * HC];
        f32x2 l0 = __builtin_amdgcn_cvt_pk_f32_fp8(u0, false);
        f32x2 h0 = __builtin_amdgcn_cvt_pk_f32_fp8(u0, true);
        f32x2 l1 = __builtin_amdgcn_cvt_pk_f32_fp8(u1, false);
        f32x2 h1 = __builtin_amdgcn_cvt_pk_f32_fp8(u1, true);
        f32x2 l2 = __builtin_amdgcn_cvt_pk_f32_fp8(u2, false);
        f32x2 h2 = __builtin_amdgcn_cvt_pk_f32_fp8(u2, true);
        f32x2 l3 = __builtin_amdgcn_cvt_pk_f32_fp8(u3, false);
        f32x2 h3 = __builtin_amdgcn_cvt_pk_f32_fp8(u3, true);
        ax += a0 * l0.x + a1 * l1.x + a2 * l2.x + a3 * l3.x;
        ay += a0 * l0.y + a1 * l1.y + a2 * l2.y + a3 * l3.y;
        az += a0 * h0.x + a1 * h1.x + a2 * h2.x + a3 * h3.x;
        aw += a0 * h0.y + a1 * h1.y + a2 * h2.y + a3 * h3.y;
    }
    for (; e < end; ++e) {
        int s0 = colsrc[e];
        float a0 = alpha[(size_t)e * 4 + head];
        unsigned u0 = *(const unsigned*)&zh[(size_t)s0 * HC];
        f32x2 l0 = __builtin_amdgcn_cvt_pk_f32_fp8(u0, false);
        f32x2 h0 = __builtin_amdgcn_cvt_pk_f32_fp8(u0, true);
        ax += a0 * l0.x; ay += a0 * l0.y; az += a0 * h0.x; aw += a0 * h0.y;
    }
    const float di = dinv[node * 4 + head];
    const int col = head * 128 + (lane << 2);
    float4 bv = *(const float4*)&bias[col];
    float rx = fmaxf(ax * di + bv.x, 0.f), ry = fmaxf(ay * di + bv.y, 0.f);
    float rz = fmaxf(az * di + bv.z, 0.f), rw = fmaxf(aw * di + bv.w, 0.f);
    us4 h;
    if (obf16) {
        h.x = f2bf(rx); h.y = f2bf(ry); h.z = f2bf(rz); h.w = f2bf(rw);
    } else {
        h.x = f2h(rx); h.y = f2h(ry); h.z = f2h(rz); h.w = f2h(rw);
    }
    __builtin_nontemporal_store(h, (us4*)&o16[(size_t)node * HC + col]);
}

// ---------------- pooling (bf16 input) / classifier ----------------
__global__ void k_gcnt(const int* __restrict__ batch, int* __restrict__ gcnt) {
    int n = blockIdx.x * blockDim.x + threadIdx.x;
    if (n < NN) atomicAdd(&gcnt[batch[n]], 1);
}

__global__ __launch_bounds__(128) void k_pool(const ushort* __restrict__ h,
                                              const int* __restrict__ goff,
                                              const int* __restrict__ gcnt,
                                              float* __restrict__ hg) {
    const int g = blockIdx.x;
    const int tid = threadIdx.x;
    const int beg = goff[g];
    const int cnt = gcnt[g];
    float4 acc = make_float4(0.f, 0.f, 0.f, 0.f);
    for (int r = beg; r < beg + cnt; ++r) {
        ushort4 v = *(const ushort4*)&h[(size_t)r * HC + (tid << 2)];
        acc.x += bf2f(v.x); acc.y += bf2f(v.y);
        acc.z += bf2f(v.z); acc.w += bf2f(v.w);
    }
    float inv = 1.0f / (float)max(cnt, 1);
    *(float4*)&hg[(size_t)g * HC + (tid << 2)] =
        make_float4(acc.x * inv, acc.y * inv, acc.z * inv, acc.w * inv);
}

__global__ __launch_bounds__(64) void k_cls(const float* __restrict__ hg,
                                            const float* __restrict__ Wc,
                                            const float* __restrict__ bc,
                                            float* __restrict__ out) {
    const int g = blockIdx.x;
    const int lane = threadIdx.x;
#pragma unroll 1
    for (int cls = 0; cls < NCLS; ++cls) {
        float p = 0.f;
#pragma unroll
        for (int j = 0; j < 8; ++j) {
            int c = lane + j * 64;
            p += hg[(size_t)g * HC + c] * Wc[c * NCLS + cls];
        }
#pragma unroll
        for (int off = 32; off; off >>= 1) p += __shfl_down(p, off, 64);
        if (lane == 0) out[g * NCLS + cls] = p + bc[cls];
    }
}

// ---------------- launch ----------------
extern "C" void kernel_launch(void* const* d_in, const int* in_sizes, int n_in,
                              void* d_out, int out_size, void* d_ws, size_t ws_size,
                              hipStream_t stream) {
    const float* x     = (const float*)d_in[0];
    const int*   ei    = (const int*)d_in[1];
    const int*   batch = (const int*)d_in[2];
    const float* W1    = (const float*)d_in[3];
    const float* asrc1 = (const float*)d_in[4];
    const float* adst1 = (const float*)d_in[5];
    const float* b1    = (const float*)d_in[6];
    const float* W2    = (const float*)d_in[7];
    const float* asrc2 = (const float*)d_in[8];
    const float* adst2 = (const float*)d_in[9];
    const float* b2    = (const float*)d_in[10];
    const float* Wc    = (const float*)d_in[11];
    const float* bc    = (const float*)d_in[12];
    float* out = (float*)d_out;
    (void)in_sizes; (void)n_in; (void)out_size; (void)ws_size;

    // ---- region plan (sequential lifetimes on stream):
    // A @0      (25.6 MB): zf8 (fp8 z mirror, both layers)
    // B @25.6M  (51.2 MB): xf16 25.6 [cvt..GEMM1] -> h1f16 51.2 [gather1..GEMM2]
    //                      -> h2b 51.2 [gather2..pool]
    char* R = (char*)d_ws;
    const size_t MB512 = (size_t)NN * HC;        // 25.6M elements
    unsigned char* zf8 = (unsigned char*)R;
    ushort* xf16  = (ushort*)(R + MB512);
    ushort* h1f16 = (ushort*)(R + MB512);
    ushort* h2b   = (ushort*)(R + MB512);

    char* w = R + MB512 * 3;
    size_t off = 0;
    auto alloc = [&](size_t bytes) {
        void* p = w + off;
        off += (bytes + 255) & ~(size_t)255;
        return p;
    };
    float* as_b = (float*)alloc((size_t)NN * NH * 4);
    float* ad_b = (float*)alloc((size_t)NN * NH * 4);
    float* dinv = (float*)alloc((size_t)NN * NH * 4);
    int* rowptr = (int*)alloc((size_t)(NN + 1) * 4);
    int* deg    = (int*)alloc((size_t)NN * 4);
    int* colsrc = (int*)alloc((size_t)NET * 4);
    int* gcnt   = (int*)alloc((size_t)NG * 4);
    int* goff   = (int*)alloc((size_t)(NG + 1) * 4);
    int* bsum   = (int*)alloc((size_t)1024 * 4);
    int* boff   = (int*)alloc((size_t)1024 * 4);
    float* hg   = (float*)alloc((size_t)NG * HC * 4);
    ushort* W1T = (ushort*)alloc((size_t)HC * IND * 2);
    ushort* W2T = (ushort*)alloc((size_t)HC * HC * 2);
    float* alpha = (float*)alloc((size_t)NET * NH * 4);  // edge-major [NET][4]

    const int EB = 256, EG = (NET + EB - 1) / EB;
    const int MT = (NN + 63) / 64;               // 782 M-tiles (BM=64)
    const int GG = 2 * (NN >> 2);                // 2 head-pair phases
    const int NB_N = (NN + 255) / 256;           // 196 scan blocks (nodes)
    const int NB_G = (NG + 255) / 256;           // 2 scan blocks (graphs)

    // ---- conversions ----
    k_cvt_f16<<<(NN * IND / 4 + 255) / 256, 256, 0, stream>>>(x, xf16, NN * IND / 4);
    k_cvt_wT<<<(HC * IND + 255) / 256, 256, 0, stream>>>(W1, W1T, IND, 8);
    k_cvt_wT<<<(HC * HC + 255) / 256, 256, 0, stream>>>(W2, W2T, HC, 9);

    // ---- CSR build (hierarchical scan) ----
    hipMemsetAsync(deg, 0, (size_t)NN * 4, stream);
    k_deg<<<EG, EB, 0, stream>>>(ei, deg);
    k_scan_part<<<NB_N, 256, 0, stream>>>(deg, bsum, NN);
    k_scan_top<<<1, 1024, 0, stream>>>(bsum, boff, rowptr, NB_N, NN);
    k_scan_out<<<NB_N, 256, 0, stream>>>(deg, boff, rowptr, NN);
    hipMemsetAsync(deg, 0, (size_t)NN * 4, stream);
    k_fill<<<EG, EB, 0, stream>>>(ei, rowptr, deg, colsrc);

    // ---- graph offsets ----
    hipMemsetAsync(gcnt, 0, (size_t)NG * 4, stream);
    k_gcnt<<<(NN + 255) / 256, 256, 0, stream>>>(batch, gcnt);
    k_scan_part<<<NB_G, 256, 0, stream>>>(gcnt, bsum, NG);
    k_scan_top<<<1, 1024, 0, stream>>>(bsum, boff, goff, NB_G, NG);
    k_scan_out<<<NB_G, 256, 0, stream>>>(gcnt, boff, goff, NG);

    // ================= layer 1 =================
    k_gemm_f16<<<MT * 4, 256, 0, stream>>>(xf16, W1T, asrc1, adst1,
                                           zf8, as_b, ad_b, NN, IND);
    k_stats<<<(NN + 63) / 64, 256, 0, stream>>>(as_b, ad_b, rowptr, colsrc,
                                                alpha, dinv, NN);
    k_gather<<<GG, 256, 0, stream>>>(zf8, alpha, dinv, rowptr, colsrc, b1,
                                     h1f16, 0);

    // ================= layer 2 =================
    k_gemm_f16<<<MT * 4, 256, 0, stream>>>(h1f16, W2T, asrc2, adst2,
                                           zf8, as_b, ad_b, NN, HC);
    k_stats<<<(NN + 63) / 64, 256, 0, stream>>>(as_b, ad_b, rowptr, colsrc,
                                                alpha, dinv, NN);
    k_gather<<<GG, 256, 0, stream>>>(zf8, alpha, dinv, rowptr, colsrc, b2,
                                     h2b, 1);

    // ================= pool + classify =================
    k_pool<<<NG, 128, 0, stream>>>(h2b, goff, gcnt, hg);
    k_cls<<<NG, 64, 0, stream>>>(hg, Wc, bc, out);
}

// Round 12
// 394.239 us; speedup vs baseline: 1.3245x; 1.0354x over previous
//
#include <hip/hip_runtime.h>

// ---------------- problem constants ----------------
#define NN      50000      // nodes
#define NE      500000     // edges (before self loops)
#define NET     550000     // edges + self loops
#define IND     256        // input dim
#define HC      512        // heads*hidden
#define NH      4          // heads
#define NG      512        // graphs
#define NCLS    10

typedef __attribute__((ext_vector_type(8))) _Float16 f16x8;
typedef __attribute__((ext_vector_type(4))) float f32x4;
typedef __attribute__((ext_vector_type(2))) float f32x2;
typedef __attribute__((ext_vector_type(4))) ushort us4;

// ---------------- scalar convert helpers ----------------
__device__ __forceinline__ ushort f2bf(float x) {      // fp32 -> bf16 (RNE)
    unsigned u = __float_as_uint(x);
    u += 0x7fffu + ((u >> 16) & 1u);
    return (ushort)(u >> 16);
}
__device__ __forceinline__ float bf2f(ushort h) {
    return __uint_as_float((unsigned)h << 16);
}
__device__ __forceinline__ ushort f2h(float x) {       // fp32 -> fp16 bits (RNE)
    union { _Float16 h; ushort u; } cv;
    cv.h = (_Float16)x;
    return cv.u;
}
__device__ __forceinline__ float h2f(ushort u) {       // fp16 bits -> fp32
    union { ushort u; _Float16 h; } cv;
    cv.u = u;
    return (float)cv.h;
}

// async global->LDS, 16B per lane. dst must be wave-uniform base (+lane*16 by HW).
__device__ __forceinline__ void gload_lds16(const void* g, void* s) {
    __builtin_amdgcn_global_load_lds(
        (const __attribute__((address_space(1))) unsigned*)g,
        (__attribute__((address_space(3))) unsigned*)s, 16, 0, 0);
}

// ---------------- fp16 MFMA GEMM + fused attention coefficients ----------
// zf8[M,512] = fp8_e4m3(A[M,K] @ B[K,512]);  as/ad[row,head] from fp32 acc
// (exact, pre-quantization).
// BM=64, BN=128, BK=64; 256 thr = 4 waves (2x2 of 32x64); LDS 24.5 KB ->
// 6 blocks/CU. 16x16x32 f16 MFMA.
__global__ __launch_bounds__(256) void k_gemm_f16(
    const ushort* __restrict__ A, const ushort* __restrict__ BT,
    const float* __restrict__ a_srcv, const float* __restrict__ a_dstv,
    unsigned char* __restrict__ Cf8, float* __restrict__ as_b,
    float* __restrict__ ad_b, int M, int K)
{
    __shared__ __align__(16) ushort As[64 * 64];     // 8 KB
    __shared__ __align__(16) ushort Bs[128 * 64];    // 16 KB
    __shared__ float sred[2][64];                    // 0.5 KB

    const int tid = threadIdx.x;
    const int nwg = gridDim.x;                       // 3128, divisible by 8
    const int orig = blockIdx.x;
    const int q = nwg >> 3, r = nwg & 7, xcd = orig & 7;
    const int wgid = (xcd < r ? xcd * (q + 1) : r * (q + 1) + (xcd - r) * q) + (orig >> 3);
    const int bm = (wgid >> 2) * 64;
    const int bn = (wgid & 3) * 128;

    const int l = tid & 63;
    const int w = tid >> 6;
    const int wm = (w >> 1) * 32, wn = (w & 1) * 64;
    const int fr = l & 15;
    const int fk = (l >> 4) * 8;

    if (tid < 64) { sred[0][tid] = 0.f; sred[1][tid] = 0.f; }

    f32x4 zero = {0.f, 0.f, 0.f, 0.f};
    f32x4 acc[2][4];
#pragma unroll
    for (int m = 0; m < 2; ++m)
#pragma unroll
        for (int n = 0; n < 4; ++n) acc[m][n] = zero;

    const int nsteps = K >> 6;
    const int wbase = (tid & 0xC0) << 4;       // wave-uniform byte base

    for (int ks = 0; ks < nsteps; ++ks) {
        int k0 = ks << 6;
#pragma unroll
        for (int i = 0; i < 2; ++i) {
            int c = i * 256 + tid;
            int row = c >> 3;
            int col16 = (c & 7) ^ (row & 7);
            int arow = bm + row; arow = arow < M ? arow : M - 1;
            gload_lds16(A + (size_t)arow * K + k0 + (col16 << 3),
                        (char*)As + i * 4096 + wbase);
        }
#pragma unroll
        for (int i = 0; i < 4; ++i) {
            int c = i * 256 + tid;
            int j = c >> 3;
            int col16 = (c & 7) ^ (j & 7);
            gload_lds16(BT + (size_t)(bn + j) * K + k0 + (col16 << 3),
                        (char*)Bs + i * 4096 + wbase);
        }
        __syncthreads();
#pragma unroll
        for (int kk = 0; kk < 64; kk += 32) {
            f16x8 a[2], b[4];
            int kb = (kk + fk) >> 3;
#pragma unroll
            for (int m = 0; m < 2; ++m) {
                int row = wm + m * 16 + fr;
                a[m] = *(const f16x8*)((const char*)As + row * 128 + ((kb ^ (row & 7)) << 4));
            }
#pragma unroll
            for (int n = 0; n < 4; ++n) {
                int col = wn + n * 16 + fr;
                b[n] = *(const f16x8*)((const char*)Bs + col * 128 + ((kb ^ (col & 7)) << 4));
            }
#pragma unroll
            for (int m = 0; m < 2; ++m)
#pragma unroll
                for (int n = 0; n < 4; ++n)
                    acc[m][n] = __builtin_amdgcn_mfma_f32_16x16x32_f16(a[m], b[n], acc[m][n], 0, 0, 0);
        }
        __syncthreads();
    }

    // ---- epilogue: fp8 z mirror + fused as/ad (from exact fp32 acc) ----
    const int hh = bn >> 7;                    // this block's head
    float asl[4], adl[4];
#pragma unroll
    for (int n = 0; n < 4; ++n) {
        int c = wn + n * 16 + fr;
        asl[n] = a_srcv[hh * 128 + c];
        adl[n] = a_dstv[hh * 128 + c];
    }
    const int rbase = (l >> 4) * 4;
#pragma unroll
    for (int m = 0; m < 2; ++m) {
#pragma unroll
        for (int rr = 0; rr < 4; ++rr) {
            int rloc = wm + m * 16 + rbase + rr;
            int rowi = bm + rloc;
            float ps = 0.f, pd = 0.f;
#pragma unroll
            for (int n = 0; n < 4; ++n) {
                float v = acc[m][n][rr];
                ps += v * asl[n];
                pd += v * adl[n];
                if (rowi < M) {
                    int pk = __builtin_amdgcn_cvt_pk_fp8_f32(v, v, 0, false);
                    Cf8[(size_t)rowi * HC + bn + wn + n * 16 + fr] = (unsigned char)pk;
                }
            }
#pragma unroll
            for (int off = 1; off < 16; off <<= 1) {
                ps += __shfl_xor(ps, off, 64);
                pd += __shfl_xor(pd, off, 64);
            }
            if (fr == 0) {
                atomicAdd(&sred[0][rloc], ps);
                atomicAdd(&sred[1][rloc], pd);
            }
        }
    }
    __syncthreads();
    if (tid < 64) {
        int rowi = bm + tid;
        if (rowi < M) {
            as_b[rowi * 4 + hh] = sred[0][tid];
            ad_b[rowi * 4 + hh] = sred[1][tid];
        }
    }
}

// ---------------- conversions ----------------
__global__ void k_cvt_f16(const float* __restrict__ in, ushort* __restrict__ o,
                          int n4) {
    int i = blockIdx.x * blockDim.x + threadIdx.x;
    if (i >= n4) return;
    float4 v = ((const float4*)in)[i];
    ushort4 h;
    h.x = f2h(v.x); h.y = f2h(v.y); h.z = f2h(v.z); h.w = f2h(v.w);
    ((ushort4*)o)[i] = h;
}

// W[K][512] -> WT[512][K] fp16
__global__ void k_cvt_wT(const float* __restrict__ W, ushort* __restrict__ hT,
                         int K, int logK) {
    int id = blockIdx.x * blockDim.x + threadIdx.x;
    if (id >= (HC << logK)) return;
    int nn = id >> logK, k = id & (K - 1);
    hT[id] = f2h(W[(size_t)k * HC + nn]);
}

// ---------------- CSR build ----------------
__global__ void k_deg(const int* __restrict__ ei, int* __restrict__ deg) {
    int e = blockIdx.x * blockDim.x + threadIdx.x;
    if (e >= NET) return;
    int d = (e < NE) ? ei[NE + e] : (e - NE);
    atomicAdd(&deg[d], 1);
}

// ---- hierarchical exclusive scan (3 kernels) ----
__global__ __launch_bounds__(256) void k_scan_part(const int* __restrict__ cnt,
                                                   int* __restrict__ bsum, int n) {
    __shared__ int red[256];
    const int tid = threadIdx.x;
    int i = blockIdx.x * 256 + tid;
    red[tid] = (i < n) ? cnt[i] : 0;
    __syncthreads();
#pragma unroll
    for (int d = 128; d; d >>= 1) {
        if (tid < d) red[tid] += red[tid + d];
        __syncthreads();
    }
    if (tid == 0) bsum[blockIdx.x] = red[0];
}

__global__ __launch_bounds__(1024) void k_scan_top(const int* __restrict__ bsum,
                                                   int* __restrict__ boff,
                                                   int* __restrict__ off, int nb, int n) {
    __shared__ int s[1024];
    const int tid = threadIdx.x;
    int v = (tid < nb) ? bsum[tid] : 0;
    s[tid] = v;
    __syncthreads();
    for (int d = 1; d < 1024; d <<= 1) {
        int t = (tid >= d) ? s[tid - d] : 0;
        __syncthreads();
        s[tid] += t;
        __syncthreads();
    }
    if (tid < nb) boff[tid] = s[tid] - v;
    if (tid == nb - 1) off[n] = s[tid];
}

__global__ __launch_bounds__(256) void k_scan_out(const int* __restrict__ cnt,
                                                  const int* __restrict__ boff,
                                                  int* __restrict__ off, int n) {
    __shared__ int s[256];
    const int tid = threadIdx.x;
    int i = blockIdx.x * 256 + tid;
    int v = (i < n) ? cnt[i] : 0;
    s[tid] = v;
    __syncthreads();
    for (int d = 1; d < 256; d <<= 1) {
        int t = (tid >= d) ? s[tid - d] : 0;
        __syncthreads();
        s[tid] += t;
        __syncthreads();
    }
    if (i < n) off[i] = boff[blockIdx.x] + s[tid] - v;
}

// colsrc as ushort: NN = 50000 < 65536
__global__ void k_fill(const int* __restrict__ ei,
                       const int* __restrict__ rowptr,
                       int* __restrict__ fillcnt,
                       ushort* __restrict__ colsrc) {
    int e = blockIdx.x * blockDim.x + threadIdx.x;
    if (e >= NET) return;
    int s, d;
    if (e < NE) { s = ei[e]; d = ei[NE + e]; } else { s = d = e - NE; }
    int pos = rowptr[d] + atomicAdd(&fillcnt[d], 1);
    colsrc[pos] = (ushort)s;
}

// ---------------- alpha + inverse-denominator precompute ----------------
// Unnormalized softmax (no max pass: |e| <~ 2 by construction, fp32-safe,
// softmax shift-invariant). alpha fp16 edge-major [NET][4]; 4 lanes per node.
__global__ __launch_bounds__(256) void k_stats(
    const float* __restrict__ as, const float* __restrict__ ad,
    const int* __restrict__ rowptr, const ushort* __restrict__ colsrc,
    ushort* __restrict__ alpha, float* __restrict__ dinv, int N)
{
    const int n = blockIdx.x * 64 + (threadIdx.x >> 2);
    if (n >= N) return;
    const int h = threadIdx.x & 3;
    const int beg = rowptr[n], end = rowptr[n + 1];
    const float adn = ad[n * 4 + h];
    float sum = 0.f;
    for (int e = beg; e < end; ++e) {
        float ev = as[(int)colsrc[e] * 4 + h] + adn;
        ev = ev > 0.f ? ev : 0.2f * ev;
        float a = __expf(ev);
        alpha[(size_t)e * 4 + h] = f2h(a);
        sum += a;
    }
    dinv[n * 4 + h] = 1.0f / (sum + 1e-16f);
}

// ---------------- fp8 weighted gather ----------------
// Block = 256 thr = 8 subgroups of 32 = 4 nodes x 2 heads (same node's two
// heads share a wave). 2 head-pair phases -> fp8 z working set 12.8 MB/phase.
// 8-wide unroll for load-latency hiding. obf16=0: fp16 out; obf16=1: bf16 out.
__global__ __launch_bounds__(256) void k_gather(
    const unsigned char* __restrict__ zf8, const ushort* __restrict__ alpha,
    const float* __restrict__ dinv, const int* __restrict__ rowptr,
    const ushort* __restrict__ colsrc, const float* __restrict__ bias,
    ushort* __restrict__ o16, int obf16)
{
    const int npb = NN >> 2;                   // 12500 blocks per phase
    const int hp = blockIdx.x / npb;           // head-pair phase (0,1)
    const int sub = threadIdx.x >> 5;
    const int node = (blockIdx.x % npb) * 4 + (sub >> 1);
    const int head = hp * 2 + (sub & 1);
    const int lane = threadIdx.x & 31;
    const int beg = rowptr[node], end = rowptr[node + 1];
    const unsigned char* __restrict__ zh = zf8 + head * 128 + (lane << 2);

    float ax = 0.f, ay = 0.f, az = 0.f, aw = 0.f;
    int e = beg;
    for (; e + 8 <= end; e += 8) {
        int s[8];
        float a[8];
        unsigned u[8];
#pragma unroll
        for (int j = 0; j < 8; ++j) {
            s[j] = colsrc[e + j];
            a[j] = h2f(alpha[(size_t)(e + j) * 4 + head]);
        }
#pragma unroll
        for (int j = 0; j < 8; ++j) u[j] = *(const unsigned*)&zh[(size_t)s[j] * HC];
#pragma unroll
        for (int j = 0; j < 8; ++j) {
            f32x2 lo = __builtin_amdgcn_cvt_pk_f32_fp8(u[j], false);
            f32x2 hi = __builtin_amdgcn_cvt_pk_f32_fp8(u[j], true);
            ax += a[j] * lo.x; ay += a[j] * lo.y;
            az += a[j] * hi.x; aw += a[j] * hi.y;
        }
    }
    for (; e + 2 <= end; e += 2) {
        int s0 = colsrc[e], s1 = colsrc[e + 1];
        float a0 = h2f(alpha[(size_t)e * 4 + head]);
        float a1 = h2f(alpha[(size_t)(e + 1) * 4 + head]);
        unsigned u0 = *(const unsigned*)&zh[(size_t)s0 * HC];
        unsigned u1 = *(const unsigned*)&zh[(size_t)s1 * HC];
        f32x2 l0 = __builtin_amdgcn_cvt_pk_f32_fp8(u0, false);
        f32x2 h0 = __builtin_amdgcn_cvt_pk_f32_fp8(u0, true);
        f32x2 l1 = __builtin_amdgcn_cvt_pk_f32_fp8(u1, false);
        f32x2 h1 = __builtin_amdgcn_cvt_pk_f32_fp8(u1, true);
        ax += a0 * l0.x + a1 * l1.x; ay += a0 * l0.y + a1 * l1.y;
        az += a0 * h0.x + a1 * h1.x; aw += a0 * h0.y + a1 * h1.y;
    }
    if (e < end) {
        int s0 = colsrc[e];
        float a0 = h2f(alpha[(size_t)e * 4 + head]);
        unsigned u0 = *(const unsigned*)&zh[(size_t)s0 * HC];
        f32x2 l0 = __builtin_amdgcn_cvt_pk_f32_fp8(u0, false);
        f32x2 h0 = __builtin_amdgcn_cvt_pk_f32_fp8(u0, true);
        ax += a0 * l0.x; ay += a0 * l0.y; az += a0 * h0.x; aw += a0 * h0.y;
    }
    const float di = dinv[node * 4 + head];
    const int col = head * 128 + (lane << 2);
    float4 bv = *(const float4*)&bias[col];
    float rx = fmaxf(ax * di + bv.x, 0.f), ry = fmaxf(ay * di + bv.y, 0.f);
    float rz = fmaxf(az * di + bv.z, 0.f), rw = fmaxf(aw * di + bv.w, 0.f);
    us4 h;
    if (obf16) {
        h.x = f2bf(rx); h.y = f2bf(ry); h.z = f2bf(rz); h.w = f2bf(rw);
    } else {
        h.x = f2h(rx); h.y = f2h(ry); h.z = f2h(rz); h.w = f2h(rw);
    }
    __builtin_nontemporal_store(h, (us4*)&o16[(size_t)node * HC + col]);
}

// ---------------- pooling (bf16 input) / classifier ----------------
__global__ void k_gcnt(const int* __restrict__ batch, int* __restrict__ gcnt) {
    int n = blockIdx.x * blockDim.x + threadIdx.x;
    if (n < NN) atomicAdd(&gcnt[batch[n]], 1);
}

__global__ __launch_bounds__(128) void k_pool(const ushort* __restrict__ h,
                                              const int* __restrict__ goff,
                                              const int* __restrict__ gcnt,
                                              float* __restrict__ hg) {
    const int g = blockIdx.x;
    const int tid = threadIdx.x;
    const int beg = goff[g];
    const int cnt = gcnt[g];
    float4 acc = make_float4(0.f, 0.f, 0.f, 0.f);
    for (int r = beg; r < beg + cnt; ++r) {
        ushort4 v = *(const ushort4*)&h[(size_t)r * HC + (tid << 2)];
        acc.x += bf2f(v.x); acc.y += bf2f(v.y);
        acc.z += bf2f(v.z); acc.w += bf2f(v.w);
    }
    float inv = 1.0f / (float)max(cnt, 1);
    *(float4*)&hg[(size_t)g * HC + (tid << 2)] =
        make_float4(acc.x * inv, acc.y * inv, acc.z * inv, acc.w * inv);
}

__global__ __launch_bounds__(64) void k_cls(const float* __restrict__ hg,
                                            const float* __restrict__ Wc,
                                            const float* __restrict__ bc,
                                            float* __restrict__ out) {
    const int g = blockIdx.x;
    const int lane = threadIdx.x;
#pragma unroll 1
    for (int cls = 0; cls < NCLS; ++cls) {
        float p = 0.f;
#pragma unroll
        for (int j = 0; j < 8; ++j) {
            int c = lane + j * 64;
            p += hg[(size_t)g * HC + c] * Wc[c * NCLS + cls];
        }
#pragma unroll
        for (int off = 32; off; off >>= 1) p += __shfl_down(p, off, 64);
        if (lane == 0) out[g * NCLS + cls] = p + bc[cls];
    }
}

// ---------------- launch ----------------
extern "C" void kernel_launch(void* const* d_in, const int* in_sizes, int n_in,
                              void* d_out, int out_size, void* d_ws, size_t ws_size,
                              hipStream_t stream) {
    const float* x     = (const float*)d_in[0];
    const int*   ei    = (const int*)d_in[1];
    const int*   batch = (const int*)d_in[2];
    const float* W1    = (const float*)d_in[3];
    const float* asrc1 = (const float*)d_in[4];
    const float* adst1 = (const float*)d_in[5];
    const float* b1    = (const float*)d_in[6];
    const float* W2    = (const float*)d_in[7];
    const float* asrc2 = (const float*)d_in[8];
    const float* adst2 = (const float*)d_in[9];
    const float* b2    = (const float*)d_in[10];
    const float* Wc    = (const float*)d_in[11];
    const float* bc    = (const float*)d_in[12];
    float* out = (float*)d_out;
    (void)in_sizes; (void)n_in; (void)out_size; (void)ws_size;

    // ---- region plan (sequential lifetimes on stream):
    // A @0      (25.6 MB): zf8 (fp8 z mirror, both layers)
    // B @25.6M  (51.2 MB): xf16 25.6 [cvt..GEMM1] -> h1f16 51.2 [gather1..GEMM2]
    //                      -> h2b 51.2 [gather2..pool]
    char* R = (char*)d_ws;
    const size_t MB512 = (size_t)NN * HC;        // 25.6M elements
    unsigned char* zf8 = (unsigned char*)R;
    ushort* xf16  = (ushort*)(R + MB512);
    ushort* h1f16 = (ushort*)(R + MB512);
    ushort* h2b   = (ushort*)(R + MB512);

    char* w = R + MB512 * 3;
    size_t off = 0;
    auto alloc = [&](size_t bytes) {
        void* p = w + off;
        off += (bytes + 255) & ~(size_t)255;
        return p;
    };
    float* as_b = (float*)alloc((size_t)NN * NH * 4);
    float* ad_b = (float*)alloc((size_t)NN * NH * 4);
    float* dinv = (float*)alloc((size_t)NN * NH * 4);
    int* rowptr = (int*)alloc((size_t)(NN + 1) * 4);
    int* deg    = (int*)alloc((size_t)NN * 4);
    ushort* colsrc = (ushort*)alloc((size_t)NET * 2);
    int* gcnt   = (int*)alloc((size_t)NG * 4);
    int* goff   = (int*)alloc((size_t)(NG + 1) * 4);
    int* bsum   = (int*)alloc((size_t)1024 * 4);
    int* boff   = (int*)alloc((size_t)1024 * 4);
    float* hg   = (float*)alloc((size_t)NG * HC * 4);
    ushort* W1T = (ushort*)alloc((size_t)HC * IND * 2);
    ushort* W2T = (ushort*)alloc((size_t)HC * HC * 2);
    ushort* alpha = (ushort*)alloc((size_t)NET * NH * 2);  // fp16, edge-major

    const int EB = 256, EG = (NET + EB - 1) / EB;
    const int MT = (NN + 63) / 64;               // 782 M-tiles (BM=64)
    const int GG = 2 * (NN >> 2);                // 2 head-pair phases
    const int NB_N = (NN + 255) / 256;
    const int NB_G = (NG + 255) / 256;

    // ---- conversions ----
    k_cvt_f16<<<(NN * IND / 4 + 255) / 256, 256, 0, stream>>>(x, xf16, NN * IND / 4);
    k_cvt_wT<<<(HC * IND + 255) / 256, 256, 0, stream>>>(W1, W1T, IND, 8);
    k_cvt_wT<<<(HC * HC + 255) / 256, 256, 0, stream>>>(W2, W2T, HC, 9);

    // ---- CSR build (hierarchical scan) ----
    hipMemsetAsync(deg, 0, (size_t)NN * 4, stream);
    k_deg<<<EG, EB, 0, stream>>>(ei, deg);
    k_scan_part<<<NB_N, 256, 0, stream>>>(deg, bsum, NN);
    k_scan_top<<<1, 1024, 0, stream>>>(bsum, boff, rowptr, NB_N, NN);
    k_scan_out<<<NB_N, 256, 0, stream>>>(deg, boff, rowptr, NN);
    hipMemsetAsync(deg, 0, (size_t)NN * 4, stream);
    k_fill<<<EG, EB, 0, stream>>>(ei, rowptr, deg, colsrc);

    // ---- graph offsets ----
    hipMemsetAsync(gcnt, 0, (size_t)NG * 4, stream);
    k_gcnt<<<(NN + 255) / 256, 256, 0, stream>>>(batch, gcnt);
    k_scan_part<<<NB_G, 256, 0, stream>>>(gcnt, bsum, NG);
    k_scan_top<<<1, 1024, 0, stream>>>(bsum, boff, goff, NB_G, NG);
    k_scan_out<<<NB_G, 256, 0, stream>>>(gcnt, boff, goff, NG);

    // ================= layer 1 =================
    k_gemm_f16<<<MT * 4, 256, 0, stream>>>(xf16, W1T, asrc1, adst1,
                                           zf8, as_b, ad_b, NN, IND);
    k_stats<<<(NN + 63) / 64, 256, 0, stream>>>(as_b, ad_b, rowptr, colsrc,
                                                alpha, dinv, NN);
    k_gather<<<GG, 256, 0, stream>>>(zf8, alpha, dinv, rowptr, colsrc, b1,
                                     h1f16, 0);

    // ================= layer 2 =================
    k_gemm_f16<<<MT * 4, 256, 0, stream>>>(h1f16, W2T, asrc2, adst2,
                                           zf8, as_b, ad_b, NN, HC);
    k_stats<<<(NN + 63) / 64, 256, 0, stream>>>(as_b, ad_b, rowptr, colsrc,
                                                alpha, dinv, NN);
    k_gather<<<GG, 256, 0, stream>>>(zf8, alpha, dinv, rowptr, colsrc, b2,
                                     h2b, 1);

    // ================= pool + classify =================
    k_pool<<<NG, 128, 0, stream>>>(h2b, goff, gcnt, hg);
    k_cls<<<NG, 64, 0, stream>>>(hg, Wc, bc, out);
}